// Round 1
// baseline (18303.606 us; speedup 1.0000x reference)
//
#include <hip/hip_runtime.h>
#include <hip/hip_bf16.h>

#define NNODES 20000
#define DIN 512
#define HID 256
#define NCLS 7
#define NLAY 2
#define NEDGE 131072
#define NPAIR 8192
#define BN_EPS 1e-5f

// GEMM tiling
#define TBM 64
#define TBN 64
#define TBK 16

__device__ __forceinline__ void atomAddF(float* p, float v) {
    unsafeAtomicAdd(p, v);   // hardware global_atomic_add_f32 on gfx950
}

// ---------------------------------------------------------------------------
// Generic fp32 GEMM: C[M,N] = A[M,K] @ B[K,N] (+bias) (optional relu)
// C has leading dimension ldc (for strided writes into the `outs` buffer).
// ---------------------------------------------------------------------------
__global__ void gemm_bias(const float* __restrict__ A, const float* __restrict__ B,
                          const float* __restrict__ bias, float* __restrict__ C,
                          int M, int N, int K, int ldc, int relu)
{
    __shared__ float As[TBK][TBM + 1];
    __shared__ float Bs[TBK][TBN + 1];
    const int bm = blockIdx.x * TBM;
    const int bn = blockIdx.y * TBN;
    const int tid = threadIdx.x;
    const int tm = (tid / 16) * 4;
    const int tn = (tid % 16) * 4;
    float acc[4][4] = {};

    for (int k0 = 0; k0 < K; k0 += TBK) {
        #pragma unroll
        for (int l = 0; l < 4; ++l) {
            int idx = tid + l * 256;          // 0..1023
            int m = idx / TBK, k = idx % TBK;
            int gm = bm + m, gk = k0 + k;
            float v = 0.f;
            if (gm < M) v = A[(size_t)gm * K + gk];
            As[k][m] = v;
        }
        #pragma unroll
        for (int l = 0; l < 4; ++l) {
            int idx = tid + l * 256;
            int k = idx / TBN, n = idx % TBN;
            int gk = k0 + k, gn = bn + n;
            float v = 0.f;
            if (gn < N) v = B[(size_t)gk * N + gn];
            Bs[k][n] = v;
        }
        __syncthreads();
        #pragma unroll
        for (int k = 0; k < TBK; ++k) {
            float a[4], b[4];
            #pragma unroll
            for (int i = 0; i < 4; ++i) a[i] = As[k][tm + i];
            #pragma unroll
            for (int j = 0; j < 4; ++j) b[j] = Bs[k][tn + j];
            #pragma unroll
            for (int i = 0; i < 4; ++i)
                #pragma unroll
                for (int j = 0; j < 4; ++j)
                    acc[i][j] = fmaf(a[i], b[j], acc[i][j]);
        }
        __syncthreads();
    }
    #pragma unroll
    for (int i = 0; i < 4; ++i) {
        int gm = bm + tm + i;
        if (gm >= M) continue;
        #pragma unroll
        for (int j = 0; j < 4; ++j) {
            int gn = bn + tn + j;
            if (gn >= N) continue;
            float v = acc[i][j] + (bias ? bias[gn] : 0.f);
            if (relu) v = fmaxf(v, 0.f);
            C[(size_t)gm * ldc + gn] = v;
        }
    }
}

// ---------------------------------------------------------------------------
// Fused comp path: for edge block, A[e][k] = t[col[e]][k]*t[row[e]][k];
// acc = A @ dW; t_nxt[row[e]][:] += acc + db  (atomic)
// ---------------------------------------------------------------------------
__global__ void comp_gemm_scatter(const float* __restrict__ t, const int* __restrict__ erow,
                                  const int* __restrict__ ecol, const float* __restrict__ B,
                                  const float* __restrict__ db, float* __restrict__ outAcc,
                                  int E)
{
    __shared__ float As[TBK][TBM + 1];
    __shared__ float Bs[TBK][TBN + 1];
    __shared__ int rIdx[TBM], cIdx[TBM];
    const int be = blockIdx.x * TBM;
    const int bn = blockIdx.y * TBN;
    const int tid = threadIdx.x;
    const int tm = (tid / 16) * 4;
    const int tn = (tid % 16) * 4;

    if (tid < TBM) {
        int e = be + tid;
        rIdx[tid] = (e < E) ? erow[e] : -1;
        cIdx[tid] = (e < E) ? ecol[e] : 0;
    }
    __syncthreads();

    float acc[4][4] = {};
    for (int k0 = 0; k0 < HID; k0 += TBK) {
        #pragma unroll
        for (int l = 0; l < 4; ++l) {
            int idx = tid + l * 256;
            int m = idx / TBK, k = idx % TBK;
            int r = rIdx[m], c = cIdx[m];
            float v = 0.f;
            if (r >= 0) v = t[(size_t)r * HID + k0 + k] * t[(size_t)c * HID + k0 + k];
            As[k][m] = v;
        }
        #pragma unroll
        for (int l = 0; l < 4; ++l) {
            int idx = tid + l * 256;
            int k = idx / TBN, n = idx % TBN;
            Bs[k][n] = B[(size_t)(k0 + k) * HID + bn + n];
        }
        __syncthreads();
        #pragma unroll
        for (int k = 0; k < TBK; ++k) {
            float a[4], b[4];
            #pragma unroll
            for (int i = 0; i < 4; ++i) a[i] = As[k][tm + i];
            #pragma unroll
            for (int j = 0; j < 4; ++j) b[j] = Bs[k][tn + j];
            #pragma unroll
            for (int i = 0; i < 4; ++i)
                #pragma unroll
                for (int j = 0; j < 4; ++j)
                    acc[i][j] = fmaf(a[i], b[j], acc[i][j]);
        }
        __syncthreads();
    }
    #pragma unroll
    for (int i = 0; i < 4; ++i) {
        int e = be + tm + i;
        if (e >= E) continue;
        int r = rIdx[tm + i];
        #pragma unroll
        for (int j = 0; j < 4; ++j) {
            int gn = bn + tn + j;
            atomAddF(&outAcc[(size_t)r * HID + gn], acc[i][j] + db[gn]);
        }
    }
}

// ---------------------------------------------------------------------------
// Column statistics for BatchNorm: stats[f] += sum, stats[HID+f] += sumsq
// ---------------------------------------------------------------------------
#define STAT_ROWS 128
__global__ void colstats(const float* __restrict__ xw, float* __restrict__ stats, int M)
{
    const int f = threadIdx.x;            // one column per thread (HID == 256)
    const int r0 = blockIdx.x * STAT_ROWS;
    const int r1 = min(r0 + STAT_ROWS, M);
    float s = 0.f, sq = 0.f;
    for (int r = r0; r < r1; ++r) {
        float v = xw[(size_t)r * HID + f];
        s += v; sq += v * v;
    }
    atomAddF(&stats[f], s);
    atomAddF(&stats[HID + f], sq);
}

__global__ void bn_relu(const float* __restrict__ xw, const float* __restrict__ stats,
                        const float* __restrict__ gamma, const float* __restrict__ beta,
                        float* __restrict__ t)
{
    const int gid = blockIdx.x * blockDim.x + threadIdx.x;   // N*HID threads
    const int f = gid % HID;
    float mu = stats[f] * (1.f / NNODES);
    float var = stats[HID + f] * (1.f / NNODES) - mu * mu;
    float v = (xw[gid] - mu) * rsqrtf(var + BN_EPS) * gamma[f] + beta[f];
    t[gid] = fmaxf(v, 0.f);
}

// ---------------------------------------------------------------------------
// Degree / normalization
// ---------------------------------------------------------------------------
__global__ void deg_count(const int* __restrict__ ecol, float* __restrict__ deg)
{
    int e = blockIdx.x * blockDim.x + threadIdx.x;
    atomAddF(&deg[ecol[e]], 1.0f);
}

__global__ void deg_fin(float* __restrict__ deg, int n)
{
    int i = blockIdx.x * blockDim.x + threadIdx.x;
    if (i < n) deg[i] = rsqrtf(deg[i] + 1.0f);   // +1 self loop; deg>=1 always
}

// t_nxt = gcn_b + dinv^2 * xw   (bias + self-loop term)
__global__ void conv_init(const float* __restrict__ xw, const float* __restrict__ dinv,
                          const float* __restrict__ gb, float* __restrict__ hbuf)
{
    const int gid = blockIdx.x * blockDim.x + threadIdx.x;
    const int n = gid / HID, f = gid % HID;
    float di = dinv[n];
    hbuf[gid] = gb[f] + di * di * xw[gid];
}

// edge scatter: hbuf[col[e]] += dinv[row]*dinv[col] * xw[row[e]]
__global__ void conv_scatter(const float* __restrict__ xw, const int* __restrict__ erow,
                             const int* __restrict__ ecol, const float* __restrict__ dinv,
                             float* __restrict__ hbuf)
{
    const int gid = blockIdx.x * blockDim.x + threadIdx.x;
    const int e = gid >> 6;                 // 64 threads per edge
    const int f4 = (gid & 63) * 4;
    int r = erow[e], c = ecol[e];
    float w = dinv[r] * dinv[c];
    const float4 v = *(const float4*)&xw[(size_t)r * HID + f4];
    float* d = &hbuf[(size_t)c * HID + f4];
    atomAddF(d + 0, w * v.x);
    atomAddF(d + 1, w * v.y);
    atomAddF(d + 2, w * v.z);
    atomAddF(d + 3, w * v.w);
}

__global__ void relu_k(float* __restrict__ p, int n)
{
    int i = blockIdx.x * blockDim.x + threadIdx.x;
    if (i < n) p[i] = fmaxf(p[i], 0.f);
}

// p0[b] = concat(t[src[b]], t[dst[b]], t[src]*t[dst])
__global__ void gather_pairs(const float* __restrict__ t, const int* __restrict__ src,
                             const int* __restrict__ dst, float* __restrict__ p0)
{
    const int gid = blockIdx.x * blockDim.x + threadIdx.x;   // NPAIR*HID threads
    const int b = gid / HID, f = gid % HID;
    float a = t[(size_t)src[b] * HID + f];
    float c = t[(size_t)dst[b] * HID + f];
    float* row = p0 + (size_t)b * 3 * HID;
    row[f] = a;
    row[HID + f] = c;
    row[2 * HID + f] = a * c;
}

// out[b][c] = cls_b[c] + sum_k relu(outs[b][k]) * cls_W[k][c]
__global__ void final_cls(const float* __restrict__ outs, const float* __restrict__ clsW,
                          const float* __restrict__ clsb, float* __restrict__ out)
{
    const int gid = blockIdx.x * blockDim.x + threadIdx.x;
    if (gid >= NPAIR * NCLS) return;
    const int b = gid / NCLS, c = gid % NCLS;
    float acc = clsb[c];
    const float* row = outs + (size_t)b * 112;
    #pragma unroll 4
    for (int k = 0; k < 112; ++k)
        acc = fmaf(fmaxf(row[k], 0.f), clsW[k * NCLS + c], acc);
    out[gid] = acc;
}

// ---------------------------------------------------------------------------
extern "C" void kernel_launch(void* const* d_in, const int* in_sizes, int n_in,
                              void* d_out, int out_size, void* d_ws, size_t ws_size,
                              hipStream_t stream)
{
    const float* x        = (const float*)d_in[0];
    const int*   edges    = (const int*)  d_in[1];
    const int*   node_id  = (const int*)  d_in[2];
    const float* lin0_W   = (const float*)d_in[3];
    const float* lin0_b   = (const float*)d_in[4];
    const float* bn_gamma = (const float*)d_in[5];
    const float* bn_beta  = (const float*)d_in[6];
    const float* gcn_W    = (const float*)d_in[7];
    const float* gcn_b    = (const float*)d_in[8];
    const float* dp_W     = (const float*)d_in[9];
    const float* dp_b     = (const float*)d_in[10];
    const float* fc1_W    = (const float*)d_in[11];
    const float* fc1_b    = (const float*)d_in[12];
    const float* fc2_W    = (const float*)d_in[13];
    const float* fc2_b    = (const float*)d_in[14];
    const float* fc3_W    = (const float*)d_in[15];
    const float* fc3_b    = (const float*)d_in[16];
    const float* cls_W    = (const float*)d_in[17];
    const float* cls_b    = (const float*)d_in[18];
    float* out = (float*)d_out;

    float* ws = (float*)d_ws;
    size_t off = 0;
    float* t_cur = ws + off; off += (size_t)NNODES * HID;
    float* t_nxt = ws + off; off += (size_t)NNODES * HID;
    float* xw    = ws + off; off += (size_t)NNODES * HID;
    float* dinv  = ws + off; off += NNODES;
    float* stats = ws + off; off += 2 * HID + 32;
    float* p0    = ws + off; off += (size_t)NPAIR * 3 * HID;
    float* p1    = ws + off; off += (size_t)NPAIR * 384;
    float* p2    = ws + off; off += (size_t)NPAIR * 192;
    float* outsb = ws + off; off += (size_t)NPAIR * 112;

    const int* src = node_id;
    const int* dst = node_id + NPAIR;

    for (int i = 0; i < NCLS; ++i) {
        const int* erow = edges + (size_t)i * 2 * NEDGE;
        const int* ecol = erow + NEDGE;

        // lin0 + BN + ReLU
        gemm_bias<<<dim3(313, 4), 256, 0, stream>>>(
            x, lin0_W + (size_t)i * DIN * HID, lin0_b + i * HID, xw,
            NNODES, HID, DIN, HID, 0);
        hipMemsetAsync(stats, 0, 2 * HID * sizeof(float), stream);
        colstats<<<(NNODES + STAT_ROWS - 1) / STAT_ROWS, 256, 0, stream>>>(xw, stats, NNODES);
        bn_relu<<<(NNODES * HID) / 256, 256, 0, stream>>>(
            xw, stats, bn_gamma + i * HID, bn_beta + i * HID, t_cur);

        // degrees (same edges for both layers)
        hipMemsetAsync(dinv, 0, NNODES * sizeof(float), stream);
        deg_count<<<NEDGE / 256, 256, 0, stream>>>(ecol, dinv);
        deg_fin<<<(NNODES + 255) / 256, 256, 0, stream>>>(dinv, NNODES);

        for (int j = 0; j < NLAY; ++j) {
            const float* gW = gcn_W + ((size_t)i * NLAY + j) * HID * HID;
            const float* gb = gcn_b + ((size_t)i * NLAY + j) * HID;
            const float* dW = dp_W  + ((size_t)i * NLAY + j) * HID * HID;
            const float* db = dp_b  + ((size_t)i * NLAY + j) * HID;

            gemm_bias<<<dim3(313, 4), 256, 0, stream>>>(
                t_cur, gW, nullptr, xw, NNODES, HID, HID, HID, 0);
            conv_init<<<(NNODES * HID) / 256, 256, 0, stream>>>(xw, dinv, gb, t_nxt);
            conv_scatter<<<(NEDGE * 64) / 256, 256, 0, stream>>>(xw, erow, ecol, dinv, t_nxt);
            relu_k<<<(NNODES * HID) / 256, 256, 0, stream>>>(t_nxt, NNODES * HID);
            comp_gemm_scatter<<<dim3(NEDGE / TBM, 4), 256, 0, stream>>>(
                t_cur, erow, ecol, dW, db, t_nxt, NEDGE);

            float* tmp = t_cur; t_cur = t_nxt; t_nxt = tmp;
        }

        // edge-pair head
        gather_pairs<<<(NPAIR * HID) / 256, 256, 0, stream>>>(t_cur, src, dst, p0);
        gemm_bias<<<dim3(128, 6), 256, 0, stream>>>(
            p0, fc1_W + (size_t)i * 768 * 384, fc1_b + i * 384, p1, NPAIR, 384, 768, 384, 1);
        gemm_bias<<<dim3(128, 3), 256, 0, stream>>>(
            p1, fc2_W + (size_t)i * 384 * 192, fc2_b + i * 192, p2, NPAIR, 192, 384, 192, 1);
        gemm_bias<<<dim3(128, 1), 256, 0, stream>>>(
            p2, fc3_W + (size_t)i * 192 * 16, fc3_b + i * 16, outsb + i * 16, NPAIR, 16, 192, 112, 0);
    }

    final_cls<<<(NPAIR * NCLS + 255) / 256, 256, 0, stream>>>(outsb, cls_W, cls_b, out);
}

// Round 2
// 2462.637 us; speedup vs baseline: 7.4325x; 7.4325x over previous
//
#include <hip/hip_runtime.h>

typedef unsigned short u16;
typedef unsigned int   u32;
typedef __attribute__((ext_vector_type(8))) short short8;
typedef __attribute__((ext_vector_type(4))) float f32x4;

#define NNODES 20000
#define MPAD   20096          // 157*128
#define DIN    512
#define HID    256
#define NCLS   7
#define NLAY   2
#define NEDGE  131072
#define NPAIR  8192
#define BN_EPS 1e-5f

__device__ __forceinline__ void atomAddF(float* p, float v) { unsafeAtomicAdd(p, v); }

__device__ __forceinline__ float b2f(u16 u) {
    u32 x = ((u32)u) << 16;
    return __builtin_bit_cast(float, x);
}
__device__ __forceinline__ u16 f2b(float f) {
    u32 u = __builtin_bit_cast(u32, f);
    u32 r = u + 0x7FFFu + ((u >> 16) & 1u);
    return (u16)(r >> 16);
}
__device__ __forceinline__ float4 b2f4(ushort4 u) {
    return make_float4(b2f(u.x), b2f(u.y), b2f(u.z), b2f(u.w));
}
__device__ __forceinline__ ushort4 f2b4(float a, float b, float c, float d) {
    ushort4 o; o.x = f2b(a); o.y = f2b(b); o.z = f2b(c); o.w = f2b(d); return o;
}

__device__ __forceinline__ void async_copy16(const u16* g, u16* l) {
    __builtin_amdgcn_global_load_lds((const __attribute__((address_space(1))) void*)g,
                                     (__attribute__((address_space(3))) void*)l, 16, 0, 0);
}

// ---------------------------------------------------------------------------
// bf16 MFMA GEMM: C[M,N] = A[M,K](bf16,row-major) @ Bt[N,K](bf16,B^T rows)
// 128x128 tile, 4 waves, 4x4 16x16x32 fragments per wave. A/Bt allocations
// must be readable for gridDim*128 rows (ws buffers are padded); stores masked.
// ---------------------------------------------------------------------------
__global__ __launch_bounds__(256) void gemm_mfma(
    const u16* __restrict__ A, const u16* __restrict__ Bt,
    const float* __restrict__ bias, float* __restrict__ Cf,
    u16* __restrict__ Cb, int M, int N, int K, int relu)
{
    __shared__ u16 As[128 * 32];
    __shared__ u16 Bs[128 * 32];
    const int tid  = threadIdx.x;
    const int wave = tid >> 6;
    const int lane = tid & 63;
    const int bm = blockIdx.x * 128;
    const int bn = blockIdx.y * 128;
    const int wr = (wave >> 1) * 64;
    const int wc = (wave & 1) * 64;

    const int srow = wave * 32 + (lane >> 2);
    const int scol = (lane & 3) * 8;
    const u16* Ag0 = A  + (size_t)(bm + srow) * K + scol;
    const u16* Ag1 = Ag0 + (size_t)16 * K;
    const u16* Bg0 = Bt + (size_t)(bn + srow) * K + scol;
    const u16* Bg1 = Bg0 + (size_t)16 * K;
    u16* As0 = &As[wave * 1024];
    u16* As1 = As0 + 512;
    u16* Bs0 = &Bs[wave * 1024];
    u16* Bs1 = Bs0 + 512;

    const int fr = lane & 15;
    const int kg = (lane >> 4) * 8;

    f32x4 zero = {0.f, 0.f, 0.f, 0.f};
    f32x4 acc[4][4];
    #pragma unroll
    for (int mi = 0; mi < 4; ++mi)
        #pragma unroll
        for (int ni = 0; ni < 4; ++ni) acc[mi][ni] = zero;

    for (int k0 = 0; k0 < K; k0 += 32) {
        async_copy16(Ag0 + k0, As0);
        async_copy16(Ag1 + k0, As1);
        async_copy16(Bg0 + k0, Bs0);
        async_copy16(Bg1 + k0, Bs1);
        __syncthreads();
        short8 af[4], bfr[4];
        #pragma unroll
        for (int mi = 0; mi < 4; ++mi)
            af[mi] = *(const short8*)&As[(wr + mi * 16 + fr) * 32 + kg];
        #pragma unroll
        for (int ni = 0; ni < 4; ++ni)
            bfr[ni] = *(const short8*)&Bs[(wc + ni * 16 + fr) * 32 + kg];
        #pragma unroll
        for (int mi = 0; mi < 4; ++mi)
            #pragma unroll
            for (int ni = 0; ni < 4; ++ni)
                acc[mi][ni] = __builtin_amdgcn_mfma_f32_16x16x32_bf16(
                    af[mi], bfr[ni], acc[mi][ni], 0, 0, 0);
        __syncthreads();
    }

    const int fq = lane >> 4;
    #pragma unroll
    for (int ni = 0; ni < 4; ++ni) {
        int col = bn + wc + ni * 16 + fr;
        if (col >= N) continue;
        float bz = bias ? bias[col] : 0.f;
        #pragma unroll
        for (int mi = 0; mi < 4; ++mi) {
            int rbase = bm + wr + mi * 16 + fq * 4;
            #pragma unroll
            for (int r = 0; r < 4; ++r) {
                int row = rbase + r;
                if (row >= M) continue;
                float v = acc[mi][ni][r] + bz;
                if (relu) v = fmaxf(v, 0.f);
                size_t o = (size_t)row * N + col;
                if (Cf) Cf[o] = v;
                if (Cb) Cb[o] = f2b(v);
            }
        }
    }
}

// ---------------------------------------------------------------------------
// fp32 GEMM (kept for tiny fc3): C[M,N] = A @ B + bias, ldc-strided store
// ---------------------------------------------------------------------------
#define TBM 64
#define TBN 64
#define TBK 16
__global__ void gemm_bias(const float* __restrict__ A, const float* __restrict__ B,
                          const float* __restrict__ bias, float* __restrict__ C,
                          int M, int N, int K, int ldc, int relu)
{
    __shared__ float As[TBK][TBM + 1];
    __shared__ float Bs[TBK][TBN + 1];
    const int bm = blockIdx.x * TBM;
    const int bn = blockIdx.y * TBN;
    const int tid = threadIdx.x;
    const int tm = (tid / 16) * 4;
    const int tn = (tid % 16) * 4;
    float acc[4][4] = {};

    for (int k0 = 0; k0 < K; k0 += TBK) {
        #pragma unroll
        for (int l = 0; l < 4; ++l) {
            int idx = tid + l * 256;
            int m = idx / TBK, k = idx % TBK;
            int gm = bm + m;
            float v = 0.f;
            if (gm < M) v = A[(size_t)gm * K + k0 + k];
            As[k][m] = v;
        }
        #pragma unroll
        for (int l = 0; l < 4; ++l) {
            int idx = tid + l * 256;
            int k = idx / TBN, n = idx % TBN;
            int gn = bn + n;
            float v = 0.f;
            if (gn < N) v = B[(size_t)(k0 + k) * N + gn];
            Bs[k][n] = v;
        }
        __syncthreads();
        #pragma unroll
        for (int k = 0; k < TBK; ++k) {
            float a[4], b[4];
            #pragma unroll
            for (int i = 0; i < 4; ++i) a[i] = As[k][tm + i];
            #pragma unroll
            for (int j = 0; j < 4; ++j) b[j] = Bs[k][tn + j];
            #pragma unroll
            for (int i = 0; i < 4; ++i)
                #pragma unroll
                for (int j = 0; j < 4; ++j)
                    acc[i][j] = fmaf(a[i], b[j], acc[i][j]);
        }
        __syncthreads();
    }
    #pragma unroll
    for (int i = 0; i < 4; ++i) {
        int gm = bm + tm + i;
        if (gm >= M) continue;
        #pragma unroll
        for (int j = 0; j < 4; ++j) {
            int gn = bn + tn + j;
            if (gn >= N) continue;
            float v = acc[i][j] + (bias ? bias[gn] : 0.f);
            if (relu) v = fmaxf(v, 0.f);
            C[(size_t)gm * ldc + gn] = v;
        }
    }
}

// ---------------------------------------------------------------------------
// Setup kernels
// ---------------------------------------------------------------------------
// x[20000][512] f32 -> xb[20096][512] bf16 (pad rows zero)
__global__ void xconv(const float* __restrict__ x, u16* __restrict__ xb)
{
    int gid = blockIdx.x * blockDim.x + threadIdx.x;   // MPAD*512/4 threads
    int i4 = gid * 4;
    int row = i4 >> 9;
    float4 v = make_float4(0.f, 0.f, 0.f, 0.f);
    if (row < NNODES) v = *(const float4*)&x[i4];
    *(ushort4*)&xb[i4] = f2b4(v.x, v.y, v.z, v.w);
}

// W f32 [nm][K][N] -> Wt bf16 [nm][NP][K]
__global__ void wtrans(const float* __restrict__ W, u16* __restrict__ Wt,
                       int K, int N, int NP)
{
    __shared__ float tile[32][33];
    const int m = blockIdx.z;
    const int k0 = blockIdx.x * 32, n0 = blockIdx.y * 32;
    const float* Wm = W + (size_t)m * K * N;
    u16* Wtm = Wt + (size_t)m * NP * K;
    const int c = threadIdx.x & 31, r = threadIdx.x >> 5;   // r: 0..7
    #pragma unroll
    for (int p = 0; p < 4; ++p)
        tile[r + p * 8][c] = Wm[(size_t)(k0 + r + p * 8) * N + n0 + c];
    __syncthreads();
    #pragma unroll
    for (int p = 0; p < 4; ++p)
        Wtm[(size_t)(n0 + r + p * 8) * K + k0 + c] = f2b(tile[c][r + p * 8]);
}

// CSR build: ptrs layout [14][20001]; arrays 0..6 = by-col (class i), 7..13 = by-row
__global__ void hist(const int* __restrict__ edges, int* __restrict__ ptrs)
{
    int gid = blockIdx.x * blockDim.x + threadIdx.x;
    int i = gid >> 17, e = gid & (NEDGE - 1);
    const int* eb = edges + (size_t)i * 2 * NEDGE;
    int r = eb[e], c = eb[NEDGE + e];
    atomicAdd(&ptrs[i * 20001 + c + 1], 1);
    atomicAdd(&ptrs[(7 + i) * 20001 + r + 1], 1);
}

#define SCN 512
__global__ void scan1(int* __restrict__ ptrs, int* __restrict__ aux)
{
    __shared__ int s[SCN];
    const int a = blockIdx.y;
    const int t = threadIdx.x;
    const int idx = blockIdx.x * SCN + t;
    int* arr = ptrs + a * 20001;
    int v = (idx < 20001) ? arr[idx] : 0;
    s[t] = v;
    __syncthreads();
    for (int off = 1; off < SCN; off <<= 1) {
        int x = (t >= off) ? s[t - off] : 0;
        __syncthreads();
        s[t] += x;
        __syncthreads();
    }
    if (idx < 20001) arr[idx] = s[t];
    if (t == SCN - 1) aux[a * 40 + blockIdx.x] = s[t];
}
__global__ void scan2(int* __restrict__ aux)
{
    if (threadIdx.x != 0) return;
    int a = blockIdx.x;
    int run = 0;
    for (int b = 0; b < 40; ++b) {
        int t = aux[a * 40 + b];
        aux[a * 40 + b] = run;
        run += t;
    }
}
__global__ void scan3(int* __restrict__ ptrs, const int* __restrict__ aux)
{
    const int a = blockIdx.y;
    const int idx = blockIdx.x * SCN + threadIdx.x;
    if (idx < 20001) ptrs[a * 20001 + idx] += aux[a * 40 + blockIdx.x];
}
__global__ void curcopy(const int* __restrict__ ptrs, int* __restrict__ cur)
{
    int gid = blockIdx.x * blockDim.x + threadIdx.x;
    if (gid < 14 * 20001) cur[gid] = ptrs[gid];
}
__global__ void csrfill(const int* __restrict__ edges, int* __restrict__ cur,
                        int* __restrict__ othercol, int* __restrict__ otherrow)
{
    int gid = blockIdx.x * blockDim.x + threadIdx.x;
    int i = gid >> 17, e = gid & (NEDGE - 1);
    const int* eb = edges + (size_t)i * 2 * NEDGE;
    int r = eb[e], c = eb[NEDGE + e];
    int pc = atomicAdd(&cur[i * 20001 + c], 1);
    othercol[(size_t)i * NEDGE + pc] = r;
    int pr = atomicAdd(&cur[(7 + i) * 20001 + r], 1);
    otherrow[(size_t)i * NEDGE + pr] = c;
}
__global__ void mkdinv(const int* __restrict__ ptrs, float* __restrict__ dinv)
{
    int gid = blockIdx.x * blockDim.x + threadIdx.x;
    if (gid >= NCLS * NNODES) return;
    int i = gid / NNODES, n = gid - i * NNODES;
    int d = ptrs[i * 20001 + n + 1] - ptrs[i * 20001 + n];
    dinv[gid] = rsqrtf((float)d + 1.0f);
}

// ---------------------------------------------------------------------------
// BatchNorm
// ---------------------------------------------------------------------------
#define STAT_ROWS 128
__global__ void colstats(const u16* __restrict__ xwb, float* __restrict__ stats)
{
    const int f = threadIdx.x;
    const int r0 = blockIdx.x * STAT_ROWS;
    const int r1 = min(r0 + STAT_ROWS, NNODES);
    float s = 0.f, sq = 0.f;
    for (int r = r0; r < r1; ++r) {
        float v = b2f(xwb[(size_t)r * HID + f]);
        s += v; sq += v * v;
    }
    atomAddF(&stats[f], s);
    atomAddF(&stats[HID + f], sq);
}
__global__ void bn_relu(const u16* __restrict__ xwb, const float* __restrict__ stats,
                        const float* __restrict__ gamma, const float* __restrict__ beta,
                        u16* __restrict__ tb)
{
    const int gid = blockIdx.x * blockDim.x + threadIdx.x;   // NNODES*64
    const int n = gid >> 6, f4 = (gid & 63) * 4;
    const float invN = 1.0f / NNODES;
    float4 su = *(const float4*)&stats[f4];
    float4 sq = *(const float4*)&stats[HID + f4];
    float4 g  = *(const float4*)&gamma[f4];
    float4 be = *(const float4*)&beta[f4];
    ushort4 u = *(const ushort4*)&xwb[(size_t)n * HID + f4];
    float4 x = b2f4(u);
    float o[4];
    float mu, var;
    mu = su.x * invN; var = sq.x * invN - mu * mu;
    o[0] = fmaxf((x.x - mu) * rsqrtf(var + BN_EPS) * g.x + be.x, 0.f);
    mu = su.y * invN; var = sq.y * invN - mu * mu;
    o[1] = fmaxf((x.y - mu) * rsqrtf(var + BN_EPS) * g.y + be.y, 0.f);
    mu = su.z * invN; var = sq.z * invN - mu * mu;
    o[2] = fmaxf((x.z - mu) * rsqrtf(var + BN_EPS) * g.z + be.z, 0.f);
    mu = su.w * invN; var = sq.w * invN - mu * mu;
    o[3] = fmaxf((x.w - mu) * rsqrtf(var + BN_EPS) * g.w + be.w, 0.f);
    *(ushort4*)&tb[(size_t)n * HID + f4] = f2b4(o[0], o[1], o[2], o[3]);
}

// ---------------------------------------------------------------------------
// Graph aggregation (CSR gathers, wave per node, lane = 4 features)
// ---------------------------------------------------------------------------
// prodb[n] = bf16( t[n] * sum_{e in row-CSR[n]} t[other[e]] )
__global__ void agg_prod(const u16* __restrict__ tb, const int* __restrict__ rptr,
                         const int* __restrict__ other, u16* __restrict__ prodb)
{
    const int node = blockIdx.x * 4 + (threadIdx.x >> 6);
    const int f = (threadIdx.x & 63) * 4;
    const int s0 = rptr[node], s1 = rptr[node + 1];
    float ax = 0.f, ay = 0.f, az = 0.f, aw = 0.f;
    for (int e = s0; e < s1; ++e) {
        int c = other[e];
        ushort4 u = *(const ushort4*)&tb[(size_t)c * HID + f];
        ax += b2f(u.x); ay += b2f(u.y); az += b2f(u.z); aw += b2f(u.w);
    }
    ushort4 tv = *(const ushort4*)&tb[(size_t)node * HID + f];
    *(ushort4*)&prodb[(size_t)node * HID + f] =
        f2b4(b2f(tv.x) * ax, b2f(tv.y) * ay, b2f(tv.z) * az, b2f(tv.w) * aw);
}

// tb_out[n] = bf16( relu( dinv[n]*(dinv[n]*xw[n] + sum dinv[r]*xw[r]) + gb )
//                   + msg[n] + degrow[n]*db )
__global__ void conv_gather(const u16* __restrict__ xwb, const int* __restrict__ cptr,
                            const int* __restrict__ cother, const float* __restrict__ dinv,
                            const int* __restrict__ rptr, const u16* __restrict__ msgb,
                            const float* __restrict__ gb, const float* __restrict__ db,
                            u16* __restrict__ tbout)
{
    const int node = blockIdx.x * 4 + (threadIdx.x >> 6);
    const int f = (threadIdx.x & 63) * 4;
    const float dn = dinv[node];
    const int s0 = cptr[node], s1 = cptr[node + 1];
    ushort4 su = *(const ushort4*)&xwb[(size_t)node * HID + f];
    float ax = dn * b2f(su.x), ay = dn * b2f(su.y);
    float az = dn * b2f(su.z), aw = dn * b2f(su.w);
    for (int e = s0; e < s1; ++e) {
        int r = cother[e];
        float dr = dinv[r];
        ushort4 u = *(const ushort4*)&xwb[(size_t)r * HID + f];
        ax += dr * b2f(u.x); ay += dr * b2f(u.y);
        az += dr * b2f(u.z); aw += dr * b2f(u.w);
    }
    float4 g  = *(const float4*)&gb[f];
    float4 d4 = *(const float4*)&db[f];
    float degr = (float)(rptr[node + 1] - rptr[node]);
    ushort4 mu = *(const ushort4*)&msgb[(size_t)node * HID + f];
    float ox = fmaxf(ax * dn + g.x, 0.f) + b2f(mu.x) + degr * d4.x;
    float oy = fmaxf(ay * dn + g.y, 0.f) + b2f(mu.y) + degr * d4.y;
    float oz = fmaxf(az * dn + g.z, 0.f) + b2f(mu.z) + degr * d4.z;
    float ow = fmaxf(aw * dn + g.w, 0.f) + b2f(mu.w) + degr * d4.w;
    *(ushort4*)&tbout[(size_t)node * HID + f] = f2b4(ox, oy, oz, ow);
}

// p0b[b] = concat(t[src], t[dst], t[src]*t[dst])  (bf16)
__global__ void gather_pairs(const u16* __restrict__ tb, const int* __restrict__ src,
                             const int* __restrict__ dst, u16* __restrict__ p0b)
{
    const int gid = blockIdx.x * blockDim.x + threadIdx.x;   // NPAIR*64
    const int b = gid >> 6, f = (gid & 63) * 4;
    int s = src[b], d = dst[b];
    ushort4 u1 = *(const ushort4*)&tb[(size_t)s * HID + f];
    ushort4 u2 = *(const ushort4*)&tb[(size_t)d * HID + f];
    u16* row = p0b + (size_t)b * 768;
    *(ushort4*)&row[f] = u1;
    *(ushort4*)&row[HID + f] = u2;
    *(ushort4*)&row[2 * HID + f] =
        f2b4(b2f(u1.x) * b2f(u2.x), b2f(u1.y) * b2f(u2.y),
             b2f(u1.z) * b2f(u2.z), b2f(u1.w) * b2f(u2.w));
}

__global__ void final_cls(const float* __restrict__ outs, const float* __restrict__ clsW,
                          const float* __restrict__ clsb, float* __restrict__ out)
{
    const int gid = blockIdx.x * blockDim.x + threadIdx.x;
    if (gid >= NPAIR * NCLS) return;
    const int b = gid / NCLS, c = gid % NCLS;
    float acc = clsb[c];
    const float* row = outs + (size_t)b * 112;
    #pragma unroll 4
    for (int k = 0; k < 112; ++k)
        acc = fmaf(fmaxf(row[k], 0.f), clsW[k * NCLS + c], acc);
    out[gid] = acc;
}

// ---------------------------------------------------------------------------
extern "C" void kernel_launch(void* const* d_in, const int* in_sizes, int n_in,
                              void* d_out, int out_size, void* d_ws, size_t ws_size,
                              hipStream_t stream)
{
    const float* x        = (const float*)d_in[0];
    const int*   edges    = (const int*)  d_in[1];
    const int*   node_id  = (const int*)  d_in[2];
    const float* lin0_W   = (const float*)d_in[3];
    const float* lin0_b   = (const float*)d_in[4];
    const float* bn_gamma = (const float*)d_in[5];
    const float* bn_beta  = (const float*)d_in[6];
    const float* gcn_W    = (const float*)d_in[7];
    const float* gcn_b    = (const float*)d_in[8];
    const float* dp_W     = (const float*)d_in[9];
    const float* dp_b     = (const float*)d_in[10];
    const float* fc1_W    = (const float*)d_in[11];
    const float* fc1_b    = (const float*)d_in[12];
    const float* fc2_W    = (const float*)d_in[13];
    const float* fc2_b    = (const float*)d_in[14];
    const float* fc3_W    = (const float*)d_in[15];
    const float* fc3_b    = (const float*)d_in[16];
    const float* cls_W    = (const float*)d_in[17];
    const float* cls_b    = (const float*)d_in[18];
    float* out = (float*)d_out;

    unsigned char* w = (unsigned char*)d_ws;
    auto alloc = [&](size_t bytes) {
        void* p = (void*)w;
        w += (bytes + 255) & ~(size_t)255;
        return p;
    };
    u16*   xb       = (u16*)  alloc((size_t)MPAD * DIN * 2);
    u16*   lin0Wt   = (u16*)  alloc((size_t)NCLS * HID * DIN * 2);
    u16*   gcnWt    = (u16*)  alloc((size_t)NCLS * NLAY * HID * HID * 2);
    u16*   dpWt     = (u16*)  alloc((size_t)NCLS * NLAY * HID * HID * 2);
    u16*   fc1Wt    = (u16*)  alloc((size_t)NCLS * 384 * 768 * 2);
    u16*   fc2Wt    = (u16*)  alloc((size_t)NCLS * 256 * 384 * 2);
    int*   ptrs     = (int*)  alloc((size_t)14 * 20001 * 4);
    int*   cur      = (int*)  alloc((size_t)14 * 20001 * 4);
    int*   aux      = (int*)  alloc((size_t)14 * 40 * 4);
    int*   othercol = (int*)  alloc((size_t)NCLS * NEDGE * 4);
    int*   otherrow = (int*)  alloc((size_t)NCLS * NEDGE * 4);
    float* dinv     = (float*)alloc((size_t)NCLS * NNODES * 4);
    u16*   tbA      = (u16*)  alloc((size_t)MPAD * HID * 2);
    u16*   tbB      = (u16*)  alloc((size_t)MPAD * HID * 2);
    u16*   xwb      = (u16*)  alloc((size_t)MPAD * HID * 2);
    u16*   msgb     = (u16*)  alloc((size_t)MPAD * HID * 2);
    u16*   prodb    = (u16*)  alloc((size_t)MPAD * HID * 2);
    float* stats    = (float*)alloc((size_t)2 * HID * 4);
    u16*   p0b      = (u16*)  alloc((size_t)NPAIR * 768 * 2);
    u16*   p1b      = (u16*)  alloc((size_t)NPAIR * 384 * 2);
    float* p2       = (float*)alloc((size_t)NPAIR * 192 * 4);
    float* outsb    = (float*)alloc((size_t)NPAIR * 112 * 4);

    const int* src = node_id;
    const int* dst = node_id + NPAIR;

    // ---- setup: bf16 conversions + transposed weights ----
    xconv<<<(MPAD * DIN / 4) / 256, 256, 0, stream>>>(x, xb);
    wtrans<<<dim3(16, 8, 7),   256, 0, stream>>>(lin0_W, lin0Wt, 512, 256, 256);
    wtrans<<<dim3(8, 8, 14),   256, 0, stream>>>(gcn_W,  gcnWt,  256, 256, 256);
    wtrans<<<dim3(8, 8, 14),   256, 0, stream>>>(dp_W,   dpWt,   256, 256, 256);
    wtrans<<<dim3(24, 12, 7),  256, 0, stream>>>(fc1_W,  fc1Wt,  768, 384, 384);
    wtrans<<<dim3(12, 6, 7),   256, 0, stream>>>(fc2_W,  fc2Wt,  384, 192, 256);

    // ---- setup: CSR (by-col arrays 0..6, by-row arrays 7..13) ----
    hipMemsetAsync(ptrs, 0, (size_t)14 * 20001 * 4, stream);
    hist<<<(NCLS * NEDGE) / 256, 256, 0, stream>>>(edges, ptrs);
    scan1<<<dim3(40, 14), SCN, 0, stream>>>(ptrs, aux);
    scan2<<<14, 64, 0, stream>>>(aux);
    scan3<<<dim3(40, 14), SCN, 0, stream>>>(ptrs, aux);
    curcopy<<<(14 * 20001 + 255) / 256, 256, 0, stream>>>(ptrs, cur);
    csrfill<<<(NCLS * NEDGE) / 256, 256, 0, stream>>>(edges, cur, othercol, otherrow);
    mkdinv<<<(NCLS * NNODES + 255) / 256, 256, 0, stream>>>(ptrs, dinv);

    u16* tb_cur = tbA;
    u16* tb_nxt = tbB;

    for (int i = 0; i < NCLS; ++i) {
        const int* cptr = ptrs + i * 20001;
        const int* rptr = ptrs + (7 + i) * 20001;
        const int* coth = othercol + (size_t)i * NEDGE;
        const int* roth = otherrow + (size_t)i * NEDGE;
        const float* dv = dinv + (size_t)i * NNODES;

        // lin0 + BN + ReLU
        gemm_mfma<<<dim3(157, 2), 256, 0, stream>>>(
            xb, lin0Wt + (size_t)i * HID * DIN, lin0_b + i * HID,
            nullptr, xwb, NNODES, HID, DIN, 0);
        hipMemsetAsync(stats, 0, 2 * HID * sizeof(float), stream);
        colstats<<<(NNODES + STAT_ROWS - 1) / STAT_ROWS, HID, 0, stream>>>(xwb, stats);
        bn_relu<<<(NNODES * 64) / 256, 256, 0, stream>>>(
            xwb, stats, bn_gamma + i * HID, bn_beta + i * HID, tb_cur);

        for (int j = 0; j < NLAY; ++j) {
            const u16* gWt = gcnWt + (size_t)(i * NLAY + j) * HID * HID;
            const u16* dWt = dpWt  + (size_t)(i * NLAY + j) * HID * HID;
            const float* gb = gcn_b + (i * NLAY + j) * HID;
            const float* db = dp_b  + (i * NLAY + j) * HID;

            agg_prod<<<NNODES / 4, 256, 0, stream>>>(tb_cur, rptr, roth, prodb);
            gemm_mfma<<<dim3(157, 2), 256, 0, stream>>>(
                prodb, dWt, nullptr, nullptr, msgb, NNODES, HID, HID, 0);
            gemm_mfma<<<dim3(157, 2), 256, 0, stream>>>(
                tb_cur, gWt, nullptr, nullptr, xwb, NNODES, HID, HID, 0);
            conv_gather<<<NNODES / 4, 256, 0, stream>>>(
                xwb, cptr, coth, dv, rptr, msgb, gb, db, tb_nxt);

            u16* tmp = tb_cur; tb_cur = tb_nxt; tb_nxt = tmp;
        }

        // edge-pair head
        gather_pairs<<<(NPAIR * 64) / 256, 256, 0, stream>>>(tb_cur, src, dst, p0b);
        gemm_mfma<<<dim3(64, 3), 256, 0, stream>>>(
            p0b, fc1Wt + (size_t)i * 384 * 768, fc1_b + i * 384,
            nullptr, p1b, NPAIR, 384, 768, 1);
        gemm_mfma<<<dim3(64, 2), 256, 0, stream>>>(
            p1b, fc2Wt + (size_t)i * 256 * 384, fc2_b + i * 192,
            p2, nullptr, NPAIR, 192, 384, 1);
        gemm_bias<<<dim3(128, 1), 256, 0, stream>>>(
            p2, fc3_W + (size_t)i * 192 * 16, fc3_b + i * 16,
            outsb + i * 16, NPAIR, 16, 192, 112, 0);
    }

    final_cls<<<(NPAIR * NCLS + 255) / 256, 256, 0, stream>>>(outsb, cls_W, cls_b, out);
}

// Round 3
// 1297.310 us; speedup vs baseline: 14.1089x; 1.8983x over previous
//
#include <hip/hip_runtime.h>

typedef unsigned short u16;
typedef unsigned int   u32;
typedef __attribute__((ext_vector_type(8))) short short8;
typedef __attribute__((ext_vector_type(4))) float f32x4;

#define NNODES 20000
#define MPAD   20096          // 157*128
#define DIN    512
#define HID    256
#define NCLS   7
#define NLAY   2
#define NEDGE  131072
#define NPAIR  8192
#define BN_EPS 1e-5f

__device__ __forceinline__ void atomAddF(float* p, float v) { unsafeAtomicAdd(p, v); }

__device__ __forceinline__ float b2f(u16 u) {
    u32 x = ((u32)u) << 16;
    return __builtin_bit_cast(float, x);
}
__device__ __forceinline__ u16 f2b(float f) {
    u32 u = __builtin_bit_cast(u32, f);
    u32 r = u + 0x7FFFu + ((u >> 16) & 1u);
    return (u16)(r >> 16);
}
__device__ __forceinline__ float4 b2f4(ushort4 u) {
    return make_float4(b2f(u.x), b2f(u.y), b2f(u.z), b2f(u.w));
}
__device__ __forceinline__ ushort4 f2b4(float a, float b, float c, float d) {
    ushort4 o; o.x = f2b(a); o.y = f2b(b); o.z = f2b(c); o.w = f2b(d); return o;
}

__device__ __forceinline__ void async_copy16(const u16* g, u16* l) {
    __builtin_amdgcn_global_load_lds((const __attribute__((address_space(1))) void*)g,
                                     (__attribute__((address_space(3))) void*)l, 16, 0, 0);
}

// ---------------------------------------------------------------------------
// Batched bf16 MFMA GEMM: per z: C = A[z] @ Bt[z]^T (+bias) (opt relu)
// A row-major [M][K] bf16 (stride sA elems per z; sA=0 -> shared A).
// Bt rows are B^T (output-col major) [NP>=N][K].
// Stores masked to row<M, col<N; ldc=N. A staging may read up to
// 128-aligned M rows past M -- caller guarantees readable memory.
// ---------------------------------------------------------------------------
__global__ __launch_bounds__(256) void gemm_mfma_b(
    const u16* __restrict__ A, size_t sA, const u16* __restrict__ Bt, size_t sB,
    const float* __restrict__ bias, int sBias,
    float* __restrict__ Cf, u16* __restrict__ Cb, size_t sC,
    int M, int N, int K, int relu)
{
    const int z = blockIdx.z;
    A  += (size_t)z * sA;
    Bt += (size_t)z * sB;
    if (bias) bias += (size_t)z * sBias;

    __shared__ u16 As[128 * 32];
    __shared__ u16 Bs[128 * 32];
    const int tid  = threadIdx.x;
    const int wave = tid >> 6;
    const int lane = tid & 63;
    const int bm = blockIdx.x * 128;
    const int bn = blockIdx.y * 128;
    const int wr = (wave >> 1) * 64;
    const int wc = (wave & 1) * 64;

    const int srow = wave * 32 + (lane >> 2);
    const int scol = (lane & 3) * 8;
    const u16* Ag0 = A  + (size_t)(bm + srow) * K + scol;
    const u16* Ag1 = Ag0 + (size_t)16 * K;
    const u16* Bg0 = Bt + (size_t)(bn + srow) * K + scol;
    const u16* Bg1 = Bg0 + (size_t)16 * K;
    u16* As0 = &As[wave * 1024];
    u16* As1 = As0 + 512;
    u16* Bs0 = &Bs[wave * 1024];
    u16* Bs1 = Bs0 + 512;

    const int fr = lane & 15;
    const int kg = (lane >> 4) * 8;

    f32x4 zero = {0.f, 0.f, 0.f, 0.f};
    f32x4 acc[4][4];
    #pragma unroll
    for (int mi = 0; mi < 4; ++mi)
        #pragma unroll
        for (int ni = 0; ni < 4; ++ni) acc[mi][ni] = zero;

    for (int k0 = 0; k0 < K; k0 += 32) {
        async_copy16(Ag0 + k0, As0);
        async_copy16(Ag1 + k0, As1);
        async_copy16(Bg0 + k0, Bs0);
        async_copy16(Bg1 + k0, Bs1);
        __syncthreads();
        short8 af[4], bfr[4];
        #pragma unroll
        for (int mi = 0; mi < 4; ++mi)
            af[mi] = *(const short8*)&As[(wr + mi * 16 + fr) * 32 + kg];
        #pragma unroll
        for (int ni = 0; ni < 4; ++ni)
            bfr[ni] = *(const short8*)&Bs[(wc + ni * 16 + fr) * 32 + kg];
        #pragma unroll
        for (int mi = 0; mi < 4; ++mi)
            #pragma unroll
            for (int ni = 0; ni < 4; ++ni)
                acc[mi][ni] = __builtin_amdgcn_mfma_f32_16x16x32_bf16(
                    af[mi], bfr[ni], acc[mi][ni], 0, 0, 0);
        __syncthreads();
    }

    const int fq = lane >> 4;
    #pragma unroll
    for (int ni = 0; ni < 4; ++ni) {
        int col = bn + wc + ni * 16 + fr;
        if (col >= N) continue;
        float bz = bias ? bias[col] : 0.f;
        #pragma unroll
        for (int mi = 0; mi < 4; ++mi) {
            int rbase = bm + wr + mi * 16 + fq * 4;
            #pragma unroll
            for (int r = 0; r < 4; ++r) {
                int row = rbase + r;
                if (row >= M) continue;
                float v = acc[mi][ni][r] + bz;
                if (relu) v = fmaxf(v, 0.f);
                size_t o = (size_t)z * sC + (size_t)row * N + col;
                if (Cf) Cf[o] = v;
                if (Cb) Cb[o] = f2b(v);
            }
        }
    }
}

// ---------------------------------------------------------------------------
// Fused fc1: A row b = concat(t[src[b]], t[dst[b]], t[src]*t[dst]) built in
// the staging stage. M=8192, K=768, N=384.
// ---------------------------------------------------------------------------
__global__ __launch_bounds__(256) void fc1_fused(
    const u16* __restrict__ tb, const int* __restrict__ src, const int* __restrict__ dst,
    const u16* __restrict__ Wt, const float* __restrict__ bias, u16* __restrict__ p1b)
{
    const int z = blockIdx.z;
    const u16* T = tb + (size_t)z * NNODES * HID;
    const u16* Bt = Wt + (size_t)z * 384 * 768;
    const float* bi = bias + (size_t)z * 384;
    u16* C = p1b + (size_t)z * NPAIR * 384;

    __shared__ u16 As[128 * 32];
    __shared__ u16 Bs[128 * 32];
    const int tid  = threadIdx.x;
    const int wave = tid >> 6;
    const int lane = tid & 63;
    const int bm = blockIdx.x * 128;
    const int bn = blockIdx.y * 128;
    const int wr = (wave >> 1) * 64;
    const int wc = (wave & 1) * 64;

    const int srow = wave * 32 + (lane >> 2);
    const int scol = (lane & 3) * 8;
    const int b0 = bm + srow, b1 = b0 + 16;
    const int s0i = src[b0], d0i = dst[b0];
    const int s1i = src[b1], d1i = dst[b1];

    const u16* Bg0 = Bt + (size_t)(bn + srow) * 768 + scol;
    const u16* Bg1 = Bg0 + (size_t)16 * 768;
    u16* As0 = &As[wave * 1024];
    u16* As1 = As0 + 512;
    u16* Bs0 = &Bs[wave * 1024];
    u16* Bs1 = Bs0 + 512;
    u16* Aw0 = As0 + lane * 8;     // manual-write target == async lane slot
    u16* Aw1 = As1 + lane * 8;

    const int fr = lane & 15;
    const int kg = (lane >> 4) * 8;

    f32x4 zero = {0.f, 0.f, 0.f, 0.f};
    f32x4 acc[4][4];
    #pragma unroll
    for (int mi = 0; mi < 4; ++mi)
        #pragma unroll
        for (int ni = 0; ni < 4; ++ni) acc[mi][ni] = zero;

    for (int k0 = 0; k0 < 768; k0 += 32) {
        if (k0 < 512) {
            const u16* r0p = (k0 < 256) ? (T + (size_t)s0i * HID + k0 + scol)
                                        : (T + (size_t)d0i * HID + (k0 - 256) + scol);
            const u16* r1p = (k0 < 256) ? (T + (size_t)s1i * HID + k0 + scol)
                                        : (T + (size_t)d1i * HID + (k0 - 256) + scol);
            async_copy16(r0p, As0);
            async_copy16(r1p, As1);
        } else {
            int kk = k0 - 512 + scol;
            short8 a0 = *(const short8*)&T[(size_t)s0i * HID + kk];
            short8 c0 = *(const short8*)&T[(size_t)d0i * HID + kk];
            short8 a1 = *(const short8*)&T[(size_t)s1i * HID + kk];
            short8 c1 = *(const short8*)&T[(size_t)d1i * HID + kk];
            short8 p0, p1;
            #pragma unroll
            for (int j = 0; j < 8; ++j) {
                p0[j] = (short)f2b(b2f((u16)a0[j]) * b2f((u16)c0[j]));
                p1[j] = (short)f2b(b2f((u16)a1[j]) * b2f((u16)c1[j]));
            }
            *(short8*)Aw0 = p0;
            *(short8*)Aw1 = p1;
        }
        async_copy16(Bg0 + k0, Bs0);
        async_copy16(Bg1 + k0, Bs1);
        __syncthreads();
        short8 af[4], bfr[4];
        #pragma unroll
        for (int mi = 0; mi < 4; ++mi)
            af[mi] = *(const short8*)&As[(wr + mi * 16 + fr) * 32 + kg];
        #pragma unroll
        for (int ni = 0; ni < 4; ++ni)
            bfr[ni] = *(const short8*)&Bs[(wc + ni * 16 + fr) * 32 + kg];
        #pragma unroll
        for (int mi = 0; mi < 4; ++mi)
            #pragma unroll
            for (int ni = 0; ni < 4; ++ni)
                acc[mi][ni] = __builtin_amdgcn_mfma_f32_16x16x32_bf16(
                    af[mi], bfr[ni], acc[mi][ni], 0, 0, 0);
        __syncthreads();
    }

    const int fq = lane >> 4;
    #pragma unroll
    for (int ni = 0; ni < 4; ++ni) {
        int col = bn + wc + ni * 16 + fr;
        if (col >= 384) continue;
        float bz = bi[col];
        #pragma unroll
        for (int mi = 0; mi < 4; ++mi) {
            int rbase = bm + wr + mi * 16 + fq * 4;
            #pragma unroll
            for (int r = 0; r < 4; ++r) {
                int row = rbase + r;
                float v = fmaxf(acc[mi][ni][r] + bz, 0.f);
                C[(size_t)row * 384 + col] = f2b(v);
            }
        }
    }
}

// ---------------------------------------------------------------------------
// fp32 GEMM (fc3), batched over z
// ---------------------------------------------------------------------------
#define TBM 64
#define TBN 64
#define TBK 16
__global__ void gemm_bias_b(const float* __restrict__ A, size_t sA,
                            const float* __restrict__ B, size_t sB,
                            const float* __restrict__ bias, int sBias,
                            float* __restrict__ C, size_t sC,
                            int M, int N, int K, int ldc, int relu)
{
    const int z = blockIdx.z;
    A += (size_t)z * sA; B += (size_t)z * sB;
    bias += (size_t)z * sBias; C += (size_t)z * sC;

    __shared__ float As[TBK][TBM + 1];
    __shared__ float Bs[TBK][TBN + 1];
    const int bm = blockIdx.x * TBM;
    const int bn = blockIdx.y * TBN;
    const int tid = threadIdx.x;
    const int tm = (tid / 16) * 4;
    const int tn = (tid % 16) * 4;
    float acc[4][4] = {};

    for (int k0 = 0; k0 < K; k0 += TBK) {
        #pragma unroll
        for (int l = 0; l < 4; ++l) {
            int idx = tid + l * 256;
            int m = idx / TBK, k = idx % TBK;
            int gm = bm + m;
            float v = 0.f;
            if (gm < M) v = A[(size_t)gm * K + k0 + k];
            As[k][m] = v;
        }
        #pragma unroll
        for (int l = 0; l < 4; ++l) {
            int idx = tid + l * 256;
            int k = idx / TBN, n = idx % TBN;
            int gn = bn + n;
            float v = 0.f;
            if (gn < N) v = B[(size_t)(k0 + k) * N + gn];
            Bs[k][n] = v;
        }
        __syncthreads();
        #pragma unroll
        for (int k = 0; k < TBK; ++k) {
            float a[4], b[4];
            #pragma unroll
            for (int i = 0; i < 4; ++i) a[i] = As[k][tm + i];
            #pragma unroll
            for (int j = 0; j < 4; ++j) b[j] = Bs[k][tn + j];
            #pragma unroll
            for (int i = 0; i < 4; ++i)
                #pragma unroll
                for (int j = 0; j < 4; ++j)
                    acc[i][j] = fmaf(a[i], b[j], acc[i][j]);
        }
        __syncthreads();
    }
    #pragma unroll
    for (int i = 0; i < 4; ++i) {
        int gm = bm + tm + i;
        if (gm >= M) continue;
        #pragma unroll
        for (int j = 0; j < 4; ++j) {
            int gn = bn + tn + j;
            if (gn >= N) continue;
            float v = acc[i][j] + bias[gn];
            if (relu) v = fmaxf(v, 0.f);
            C[(size_t)gm * ldc + gn] = v;
        }
    }
}

// ---------------------------------------------------------------------------
// Setup kernels
// ---------------------------------------------------------------------------
__global__ void xconv(const float* __restrict__ x, u16* __restrict__ xb)
{
    int gid = blockIdx.x * blockDim.x + threadIdx.x;
    int i4 = gid * 4;
    int row = i4 >> 9;
    float4 v = make_float4(0.f, 0.f, 0.f, 0.f);
    if (row < NNODES) v = *(const float4*)&x[i4];
    *(ushort4*)&xb[i4] = f2b4(v.x, v.y, v.z, v.w);
}

// W f32 [nm][K][N] -> Wt bf16 [nm][NP][K]
__global__ void wtrans(const float* __restrict__ W, u16* __restrict__ Wt,
                       int K, int N, int NP)
{
    __shared__ float tile[32][33];
    const int m = blockIdx.z;
    const int k0 = blockIdx.x * 32, n0 = blockIdx.y * 32;
    const float* Wm = W + (size_t)m * K * N;
    u16* Wtm = Wt + (size_t)m * NP * K;
    const int c = threadIdx.x & 31, r = threadIdx.x >> 5;
    #pragma unroll
    for (int p = 0; p < 4; ++p)
        tile[r + p * 8][c] = Wm[(size_t)(k0 + r + p * 8) * N + n0 + c];
    __syncthreads();
    #pragma unroll
    for (int p = 0; p < 4; ++p)
        Wtm[(size_t)(n0 + r + p * 8) * K + k0 + c] = f2b(tile[c][r + p * 8]);
}

// CSR build: ptrs layout [14][20001]; 0..6 = by-col (class i), 7..13 = by-row.
// Block swizzle: 3584 blocks, 8 XCDs, 448 each -> per-XCD write locality.
__device__ __forceinline__ int swz3584(int b) { return (b & 7) * 448 + (b >> 3); }

__global__ void hist(const int* __restrict__ edges, int* __restrict__ ptrs)
{
    int gid = swz3584(blockIdx.x) * 256 + threadIdx.x;
    int i = gid >> 17, e = gid & (NEDGE - 1);
    const int* eb = edges + (size_t)i * 2 * NEDGE;
    int r = eb[e], c = eb[NEDGE + e];
    atomicAdd(&ptrs[i * 20001 + c + 1], 1);
    atomicAdd(&ptrs[(7 + i) * 20001 + r + 1], 1);
}

#define SCN 512
__global__ void scan1(int* __restrict__ ptrs, int* __restrict__ aux)
{
    __shared__ int s[SCN];
    const int a = blockIdx.y;
    const int t = threadIdx.x;
    const int idx = blockIdx.x * SCN + t;
    int* arr = ptrs + a * 20001;
    int v = (idx < 20001) ? arr[idx] : 0;
    s[t] = v;
    __syncthreads();
    for (int off = 1; off < SCN; off <<= 1) {
        int x = (t >= off) ? s[t - off] : 0;
        __syncthreads();
        s[t] += x;
        __syncthreads();
    }
    if (idx < 20001) arr[idx] = s[t];
    if (t == SCN - 1) aux[a * 40 + blockIdx.x] = s[t];
}
__global__ void scan2(int* __restrict__ aux)
{
    if (threadIdx.x != 0) return;
    int a = blockIdx.x;
    int run = 0;
    for (int b = 0; b < 40; ++b) {
        int t = aux[a * 40 + b];
        aux[a * 40 + b] = run;
        run += t;
    }
}
// adds block offsets AND writes `cur` copy (fill cursors)
__global__ void scan3(int* __restrict__ ptrs, const int* __restrict__ aux,
                      int* __restrict__ cur)
{
    const int a = blockIdx.y;
    const int idx = blockIdx.x * SCN + threadIdx.x;
    if (idx < 20001) {
        int v = ptrs[a * 20001 + idx] + aux[a * 40 + blockIdx.x];
        ptrs[a * 20001 + idx] = v;
        cur[a * 20001 + idx] = v;
    }
}
__global__ void csrfill(const int* __restrict__ edges, int* __restrict__ cur,
                        int* __restrict__ othercol, int* __restrict__ otherrow)
{
    int gid = swz3584(blockIdx.x) * 256 + threadIdx.x;
    int i = gid >> 17, e = gid & (NEDGE - 1);
    const int* eb = edges + (size_t)i * 2 * NEDGE;
    int r = eb[e], c = eb[NEDGE + e];
    int pc = atomicAdd(&cur[i * 20001 + c], 1);
    othercol[(size_t)i * NEDGE + pc] = r;
    int pr = atomicAdd(&cur[(7 + i) * 20001 + r], 1);
    otherrow[(size_t)i * NEDGE + pr] = c;
}
__global__ void mkdinv(const int* __restrict__ ptrs, float* __restrict__ dinv)
{
    int gid = blockIdx.x * blockDim.x + threadIdx.x;
    if (gid >= NCLS * NNODES) return;
    int i = gid / NNODES, n = gid - i * NNODES;
    int d = ptrs[i * 20001 + n + 1] - ptrs[i * 20001 + n];
    dinv[gid] = rsqrtf((float)d + 1.0f);
}

// ---------------------------------------------------------------------------
// BatchNorm (batched over z = blockIdx.y)
// ---------------------------------------------------------------------------
#define STAT_ROWS 128
__global__ void colstats_b(const u16* __restrict__ xwb, float* __restrict__ stats)
{
    const int z = blockIdx.y;
    const int f = threadIdx.x;
    const int r0 = blockIdx.x * STAT_ROWS;
    const int r1 = min(r0 + STAT_ROWS, NNODES);
    const u16* X = xwb + (size_t)z * NNODES * HID;
    float s = 0.f, sq = 0.f;
    for (int r = r0; r < r1; ++r) {
        float v = b2f(X[(size_t)r * HID + f]);
        s += v; sq += v * v;
    }
    atomAddF(&stats[z * 2 * HID + f], s);
    atomAddF(&stats[z * 2 * HID + HID + f], sq);
}
__global__ void bn_relu_b(const u16* __restrict__ xwb, const float* __restrict__ stats,
                          const float* __restrict__ gamma, const float* __restrict__ beta,
                          u16* __restrict__ tb)
{
    const int z = blockIdx.y;
    const int gid = blockIdx.x * blockDim.x + threadIdx.x;   // NNODES*64
    const int n = gid >> 6, f4 = (gid & 63) * 4;
    const u16* X = xwb + (size_t)z * NNODES * HID;
    u16* T = tb + (size_t)z * NNODES * HID;
    const float* st = stats + z * 2 * HID;
    const float invN = 1.0f / NNODES;
    float4 su = *(const float4*)&st[f4];
    float4 sq = *(const float4*)&st[HID + f4];
    float4 g  = *(const float4*)&gamma[(size_t)z * HID + f4];
    float4 be = *(const float4*)&beta[(size_t)z * HID + f4];
    ushort4 u = *(const ushort4*)&X[(size_t)n * HID + f4];
    float4 x = b2f4(u);
    float o[4], mu, var;
    mu = su.x * invN; var = sq.x * invN - mu * mu;
    o[0] = fmaxf((x.x - mu) * rsqrtf(var + BN_EPS) * g.x + be.x, 0.f);
    mu = su.y * invN; var = sq.y * invN - mu * mu;
    o[1] = fmaxf((x.y - mu) * rsqrtf(var + BN_EPS) * g.y + be.y, 0.f);
    mu = su.z * invN; var = sq.z * invN - mu * mu;
    o[2] = fmaxf((x.z - mu) * rsqrtf(var + BN_EPS) * g.z + be.z, 0.f);
    mu = su.w * invN; var = sq.w * invN - mu * mu;
    o[3] = fmaxf((x.w - mu) * rsqrtf(var + BN_EPS) * g.w + be.w, 0.f);
    *(ushort4*)&T[(size_t)n * HID + f4] = f2b4(o[0], o[1], o[2], o[3]);
}

// ---------------------------------------------------------------------------
// Graph aggregation (batched over z = blockIdx.y; wave/node, lane = 4 feats)
// ---------------------------------------------------------------------------
__global__ void agg_prod_b(const u16* __restrict__ tb, const int* __restrict__ rptrs,
                           const int* __restrict__ roth, u16* __restrict__ prodb)
{
    const int z = blockIdx.y;
    const u16* T = tb + (size_t)z * NNODES * HID;
    const int* rptr = rptrs + (size_t)z * 20001;
    const int* oth = roth + (size_t)z * NEDGE;
    u16* P = prodb + (size_t)z * NNODES * HID;
    const int node = blockIdx.x * 4 + (threadIdx.x >> 6);
    const int f = (threadIdx.x & 63) * 4;
    const int s0 = rptr[node], s1 = rptr[node + 1];
    float ax = 0.f, ay = 0.f, az = 0.f, aw = 0.f;
    for (int e = s0; e < s1; ++e) {
        int c = oth[e];
        ushort4 u = *(const ushort4*)&T[(size_t)c * HID + f];
        ax += b2f(u.x); ay += b2f(u.y); az += b2f(u.z); aw += b2f(u.w);
    }
    ushort4 tv = *(const ushort4*)&T[(size_t)node * HID + f];
    *(ushort4*)&P[(size_t)node * HID + f] =
        f2b4(b2f(tv.x) * ax, b2f(tv.y) * ay, b2f(tv.z) * az, b2f(tv.w) * aw);
}

// out = relu(dn*(dn*xw[n] + sum dr*xw[r]) + gb) + msg(in out buf) + degrow*db
__global__ void conv_gather_b(const u16* __restrict__ xwb, const int* __restrict__ cptrs,
                              const int* __restrict__ coth, const float* __restrict__ dinv,
                              const int* __restrict__ rptrs,
                              const float* __restrict__ gb, const float* __restrict__ db,
                              u16* __restrict__ tbout)
{
    const int z = blockIdx.y;
    const u16* X = xwb + (size_t)z * NNODES * HID;
    const int* cptr = cptrs + (size_t)z * 20001;
    const int* oth = coth + (size_t)z * NEDGE;
    const float* dv = dinv + (size_t)z * NNODES;
    const int* rptr = rptrs + (size_t)z * 20001;
    const float* g4p = gb + (size_t)z * NLAY * HID;
    const float* d4p = db + (size_t)z * NLAY * HID;
    u16* O = tbout + (size_t)z * NNODES * HID;

    const int node = blockIdx.x * 4 + (threadIdx.x >> 6);
    const int f = (threadIdx.x & 63) * 4;
    const float dn = dv[node];
    const int s0 = cptr[node], s1 = cptr[node + 1];
    ushort4 su = *(const ushort4*)&X[(size_t)node * HID + f];
    float ax = dn * b2f(su.x), ay = dn * b2f(su.y);
    float az = dn * b2f(su.z), aw = dn * b2f(su.w);
    for (int e = s0; e < s1; ++e) {
        int r = oth[e];
        float dr = dv[r];
        ushort4 u = *(const ushort4*)&X[(size_t)r * HID + f];
        ax += dr * b2f(u.x); ay += dr * b2f(u.y);
        az += dr * b2f(u.z); aw += dr * b2f(u.w);
    }
    float4 g  = *(const float4*)&g4p[f];
    float4 d4 = *(const float4*)&d4p[f];
    float degr = (float)(rptr[node + 1] - rptr[node]);
    ushort4 mu = *(const ushort4*)&O[(size_t)node * HID + f];
    float ox = fmaxf(ax * dn + g.x, 0.f) + b2f(mu.x) + degr * d4.x;
    float oy = fmaxf(ay * dn + g.y, 0.f) + b2f(mu.y) + degr * d4.y;
    float oz = fmaxf(az * dn + g.z, 0.f) + b2f(mu.z) + degr * d4.z;
    float ow = fmaxf(aw * dn + g.w, 0.f) + b2f(mu.w) + degr * d4.w;
    *(ushort4*)&O[(size_t)node * HID + f] = f2b4(ox, oy, oz, ow);
}

__global__ void final_cls(const float* __restrict__ outs, const float* __restrict__ clsW,
                          const float* __restrict__ clsb, float* __restrict__ out)
{
    const int gid = blockIdx.x * blockDim.x + threadIdx.x;
    if (gid >= NPAIR * NCLS) return;
    const int b = gid / NCLS, c = gid % NCLS;
    float acc = clsb[c];
    const float* row = outs + (size_t)b * 112;
    #pragma unroll 4
    for (int k = 0; k < 112; ++k)
        acc = fmaf(fmaxf(row[k], 0.f), clsW[k * NCLS + c], acc);
    out[gid] = acc;
}

// ---------------------------------------------------------------------------
extern "C" void kernel_launch(void* const* d_in, const int* in_sizes, int n_in,
                              void* d_out, int out_size, void* d_ws, size_t ws_size,
                              hipStream_t stream)
{
    const float* x        = (const float*)d_in[0];
    const int*   edges    = (const int*)  d_in[1];
    const int*   node_id  = (const int*)  d_in[2];
    const float* lin0_W   = (const float*)d_in[3];
    const float* lin0_b   = (const float*)d_in[4];
    const float* bn_gamma = (const float*)d_in[5];
    const float* bn_beta  = (const float*)d_in[6];
    const float* gcn_W    = (const float*)d_in[7];
    const float* gcn_b    = (const float*)d_in[8];
    const float* dp_W     = (const float*)d_in[9];
    const float* dp_b     = (const float*)d_in[10];
    const float* fc1_W    = (const float*)d_in[11];
    const float* fc1_b    = (const float*)d_in[12];
    const float* fc2_W    = (const float*)d_in[13];
    const float* fc2_b    = (const float*)d_in[14];
    const float* fc3_W    = (const float*)d_in[15];
    const float* fc3_b    = (const float*)d_in[16];
    const float* cls_W    = (const float*)d_in[17];
    const float* cls_b    = (const float*)d_in[18];
    float* out = (float*)d_out;

    unsigned char* w = (unsigned char*)d_ws;
    size_t used = 0;
    auto alloc = [&](size_t bytes) {
        void* p = (void*)(w + used);
        used += (bytes + 255) & ~(size_t)255;
        return p;
    };
    u16*   xb       = (u16*)  alloc((size_t)MPAD * DIN * 2);
    u16*   lin0Wt   = (u16*)  alloc((size_t)NCLS * HID * DIN * 2);
    u16*   gcnWt    = (u16*)  alloc((size_t)NCLS * NLAY * HID * HID * 2);
    u16*   dpWt     = (u16*)  alloc((size_t)NCLS * NLAY * HID * HID * 2);
    u16*   fc1Wt    = (u16*)  alloc((size_t)NCLS * 384 * 768 * 2);
    u16*   fc2Wt    = (u16*)  alloc((size_t)NCLS * 256 * 384 * 2);
    int*   ptrs     = (int*)  alloc((size_t)14 * 20001 * 4);
    int*   cur      = (int*)  alloc((size_t)14 * 20001 * 4);
    int*   aux      = (int*)  alloc((size_t)14 * 40 * 4);
    int*   othercol = (int*)  alloc((size_t)NCLS * NEDGE * 4);
    int*   otherrow = (int*)  alloc((size_t)NCLS * NEDGE * 4);
    float* dinv     = (float*)alloc((size_t)NCLS * NNODES * 4);
    float* outsb    = (float*)alloc((size_t)NPAIR * 112 * 4);
    float* stats    = (float*)alloc((size_t)NCLS * 2 * HID * 4);

    // class-group size g chosen from remaining workspace (deterministic)
    int g = 1;
    for (int t = NCLS; t >= 1; --t) {
        size_t big = ((size_t)t * NNODES + 96) * HID * 2;
        big = (big + 255) & ~(size_t)255;
        if (used + 3 * big <= ws_size) { g = t; break; }
    }
    size_t bigBytes = ((size_t)g * NNODES + 96) * HID * 2;
    u16* tbA = (u16*)alloc(bigBytes);
    u16* tbB = (u16*)alloc(bigBytes);
    u16* pxw = (u16*)alloc(bigBytes);
    u16*   p1b = pxw;            // head stage reuse (pxw dead after layers)
    float* p2f = (float*)tbB;    // head stage reuse (tbB dead after layers)

    const int* src = node_id;
    const int* dst = node_id + NPAIR;

    // ---- setup: bf16 conversions + transposed weights ----
    xconv<<<(MPAD * DIN / 4) / 256, 256, 0, stream>>>(x, xb);
    wtrans<<<dim3(16, 8, 7),  256, 0, stream>>>(lin0_W, lin0Wt, 512, 256, 256);
    wtrans<<<dim3(8, 8, 14),  256, 0, stream>>>(gcn_W,  gcnWt,  256, 256, 256);
    wtrans<<<dim3(8, 8, 14),  256, 0, stream>>>(dp_W,   dpWt,   256, 256, 256);
    wtrans<<<dim3(24, 12, 7), 256, 0, stream>>>(fc1_W,  fc1Wt,  768, 384, 384);
    wtrans<<<dim3(12, 6, 7),  256, 0, stream>>>(fc2_W,  fc2Wt,  384, 192, 256);

    // ---- setup: CSR ----
    hipMemsetAsync(ptrs, 0, (size_t)14 * 20001 * 4, stream);
    hist<<<(NCLS * NEDGE) / 256, 256, 0, stream>>>(edges, ptrs);
    scan1<<<dim3(40, 14), SCN, 0, stream>>>(ptrs, aux);
    scan2<<<14, 64, 0, stream>>>(aux);
    scan3<<<dim3(40, 14), SCN, 0, stream>>>(ptrs, aux, cur);
    csrfill<<<(NCLS * NEDGE) / 256, 256, 0, stream>>>(edges, cur, othercol, otherrow);
    mkdinv<<<(NCLS * NNODES + 255) / 256, 256, 0, stream>>>(ptrs, dinv);

    const size_t sT = (size_t)NNODES * HID;   // per-class activation stride

    for (int cb = 0; cb < NCLS; cb += g) {
        const int gl = min(g, NCLS - cb);
        u16* tb_cur = tbA;
        u16* tb_nxt = tbB;

        // lin0 (A shared) -> pxw ; BN+ReLU -> tbA
        gemm_mfma_b<<<dim3(157, 2, gl), 256, 0, stream>>>(
            xb, 0, lin0Wt + (size_t)cb * HID * DIN, (size_t)HID * DIN,
            lin0_b + cb * HID, HID, nullptr, pxw, sT, NNODES, HID, DIN, 0);
        hipMemsetAsync(stats, 0, (size_t)gl * 2 * HID * 4, stream);
        colstats_b<<<dim3(157, gl), HID, 0, stream>>>(pxw, stats);
        bn_relu_b<<<dim3(5000, gl), 256, 0, stream>>>(
            pxw, stats, bn_gamma + cb * HID, bn_beta + cb * HID, tb_cur);

        for (int j = 0; j < NLAY; ++j) {
            const u16* gWt = gcnWt + ((size_t)cb * NLAY + j) * HID * HID;
            const u16* dWt = dpWt  + ((size_t)cb * NLAY + j) * HID * HID;
            const float* gb = gcn_b + ((size_t)cb * NLAY + j) * HID;
            const float* db = dp_b  + ((size_t)cb * NLAY + j) * HID;

            // prod = t * agg(t)  (by-row CSR)
            agg_prod_b<<<dim3(5000, gl), 256, 0, stream>>>(
                tb_cur, ptrs + (7 + cb) * 20001, otherrow + (size_t)cb * NEDGE, pxw);
            // msg = prod @ dW   -> tb_nxt (bf16, no bias)
            gemm_mfma_b<<<dim3(157, 2, gl), 256, 0, stream>>>(
                pxw, sT, dWt, (size_t)NLAY * HID * HID, nullptr, 0,
                nullptr, tb_nxt, sT, NNODES, HID, HID, 0);
            // xw = t @ gW       -> pxw
            gemm_mfma_b<<<dim3(157, 2, gl), 256, 0, stream>>>(
                tb_cur, sT, gWt, (size_t)NLAY * HID * HID, nullptr, 0,
                nullptr, pxw, sT, NNODES, HID, HID, 0);
            // tb_nxt = relu(conv) + msg + degrow*db
            conv_gather_b<<<dim3(5000, gl), 256, 0, stream>>>(
                pxw, ptrs + cb * 20001, othercol + (size_t)cb * NEDGE,
                dinv + (size_t)cb * NNODES, ptrs + (7 + cb) * 20001,
                gb, db, tb_nxt);

            u16* tmp = tb_cur; tb_cur = tb_nxt; tb_nxt = tmp;
        }
        // after even NLAY, tb_cur == tbA ; tbB and pxw are free

        // head: fused fc1 -> p1b(pxw), fc2 -> p2f(tbB), fc3 -> outsb slice
        fc1_fused<<<dim3(64, 3, gl), 256, 0, stream>>>(
            tb_cur, src, dst, fc1Wt + (size_t)cb * 384 * 768, fc1_b + cb * 384, p1b);
        gemm_mfma_b<<<dim3(64, 2, gl), 256, 0, stream>>>(
            p1b, (size_t)NPAIR * 384, fc2Wt + (size_t)cb * 256 * 384, (size_t)256 * 384,
            fc2_b + cb * 192, 192, p2f, nullptr, (size_t)NPAIR * 192,
            NPAIR, 192, 384, 1);
        gemm_bias_b<<<dim3(128, 1, gl), 256, 0, stream>>>(
            p2f, (size_t)NPAIR * 192, fc3_W + (size_t)cb * 192 * 16, (size_t)192 * 16,
            fc3_b + cb * 16, 16, outsb + cb * 16, 16,
            NPAIR, 16, 192, 112, 0);
    }

    final_cls<<<(NPAIR * NCLS + 255) / 256, 256, 0, stream>>>(outsb, cls_W, cls_b, out);
}

// Round 4
// 1137.293 us; speedup vs baseline: 16.0940x; 1.1407x over previous
//
#include <hip/hip_runtime.h>

typedef unsigned short u16;
typedef unsigned int   u32;
typedef __attribute__((ext_vector_type(8))) short short8;
typedef __attribute__((ext_vector_type(4))) float f32x4;

#define NNODES 20000
#define MPAD   20096          // 157*128
#define DIN    512
#define HID    256
#define NCLS   7
#define NLAY   2
#define NEDGE  131072
#define NPAIR  8192
#define BN_EPS 1e-5f

__device__ __forceinline__ void atomAddF(float* p, float v) { unsafeAtomicAdd(p, v); }

__device__ __forceinline__ float b2f(u16 u) {
    u32 x = ((u32)u) << 16;
    return __builtin_bit_cast(float, x);
}
__device__ __forceinline__ u16 f2b(float f) {
    u32 u = __builtin_bit_cast(u32, f);
    u32 r = u + 0x7FFFu + ((u >> 16) & 1u);
    return (u16)(r >> 16);
}
__device__ __forceinline__ float4 b2f4(ushort4 u) {
    return make_float4(b2f(u.x), b2f(u.y), b2f(u.z), b2f(u.w));
}
__device__ __forceinline__ ushort4 f2b4(float a, float b, float c, float d) {
    ushort4 o; o.x = f2b(a); o.y = f2b(b); o.z = f2b(c); o.w = f2b(d); return o;
}

__device__ __forceinline__ void async_copy16(const u16* g, u16* l) {
    __builtin_amdgcn_global_load_lds((const __attribute__((address_space(1))) void*)g,
                                     (__attribute__((address_space(3))) void*)l, 16, 0, 0);
}

// bijective chunk swizzle: orig (round-robin over 8 XCDs) -> logical id such
// that each XCD owns a contiguous logical range (m204 form)
__device__ __forceinline__ int chunk_swz(int orig, int nwg) {
    int xcd = orig & 7, q = nwg >> 3, r = nwg & 7;
    int base = (xcd < r) ? xcd * (q + 1) : r * (q + 1) + (xcd - r) * q;
    return base + (orig >> 3);
}

// ---------------------------------------------------------------------------
// Full-N bf16 MFMA GEMM (N<=256): per z: C = A[z] @ Bt[z]^T (+bias)(opt relu)
// 128-row block covers ALL N columns in one pass (A fetched exactly once).
// 4 waves: wave tile 64 rows x 128 cols, acc[4][8] 16x16x32 fragments.
// Epilogue: if Cb && N==256, repack through LDS -> coalesced 16B stores.
// A rows [bm, bm+128) must be readable (caller pads); stores masked.
// ---------------------------------------------------------------------------
__global__ __launch_bounds__(256, 2) void gemm_fn(
    const u16* __restrict__ A, size_t sA, const u16* __restrict__ Bt, size_t sB,
    const float* __restrict__ bias, int sBias,
    float* __restrict__ Cf, u16* __restrict__ Cb, size_t sC,
    int M, int N, int K, int relu)
{
    const int z = blockIdx.z;
    A  += (size_t)z * sA;
    Bt += (size_t)z * sB;
    if (bias) bias += (size_t)z * sBias;

    __shared__ u16 sm[12288];        // As: [0,4096) u16, Bs: [4096,12288)
    u16* As = sm;
    u16* Bs = sm + 4096;

    const int tid  = threadIdx.x;
    const int wave = tid >> 6;
    const int lane = tid & 63;
    const int bm = blockIdx.x * 128;
    const int wr = (wave >> 1) * 64;
    const int wc = (wave & 1) * 128;

    // A staging: 512 16B-blocks; thread t -> blocks t, t+256 (rows t>>2, t>>2+64)
    const int ar = tid >> 2, aj = (tid & 3) * 8;
    const u16* AgA = A + (size_t)(bm + ar) * K + aj;
    const u16* AgB = A + (size_t)(bm + ar + 64) * K + aj;
    u16* AsA = As + tid * 8;
    u16* AsB = As + tid * 8 + 2048;
    // B staging: 1024 16B-blocks; c-th: row c*64 + (t>>2)
    const u16* BgC[4]; u16* BsC[4];
    #pragma unroll
    for (int c = 0; c < 4; ++c) {
        BgC[c] = Bt + (size_t)(c * 64 + ar) * K + aj;
        BsC[c] = Bs + ((size_t)c * 256 + tid) * 8;
    }

    const int fr = lane & 15;
    const int fq = lane >> 4;
    const int kg = fq * 8;

    f32x4 zero = {0.f, 0.f, 0.f, 0.f};
    f32x4 acc[4][8];
    #pragma unroll
    for (int mi = 0; mi < 4; ++mi)
        #pragma unroll
        for (int ni = 0; ni < 8; ++ni) acc[mi][ni] = zero;

    for (int k0 = 0; k0 < K; k0 += 32) {
        async_copy16(AgA + k0, AsA);
        async_copy16(AgB + k0, AsB);
        #pragma unroll
        for (int c = 0; c < 4; ++c) async_copy16(BgC[c] + k0, BsC[c]);
        __syncthreads();
        short8 af[4], bfr[8];
        #pragma unroll
        for (int mi = 0; mi < 4; ++mi)
            af[mi] = *(const short8*)&As[(wr + mi * 16 + fr) * 32 + kg];
        #pragma unroll
        for (int ni = 0; ni < 8; ++ni)
            bfr[ni] = *(const short8*)&Bs[(wc + ni * 16 + fr) * 32 + kg];
        #pragma unroll
        for (int mi = 0; mi < 4; ++mi)
            #pragma unroll
            for (int ni = 0; ni < 8; ++ni)
                acc[mi][ni] = __builtin_amdgcn_mfma_f32_16x16x32_bf16(
                    af[mi], bfr[ni], acc[mi][ni], 0, 0, 0);
        __syncthreads();
    }

    float bv[8];
    #pragma unroll
    for (int ni = 0; ni < 8; ++ni) {
        int col = wc + ni * 16 + fr;
        bv[ni] = (bias && col < N) ? bias[col] : 0.f;
    }

    if (Cb && N == 256) {
        // repack through LDS: chunk = 32 rows x 256 cols bf16 (+8 u16 row pad)
        u16* R = sm;                       // 32*264 u16 = 16896B <= 24576B
        const int lrb = (wave >> 1) * 16 + fq * 4;
        const int cb0 = wc + fr;
        #pragma unroll
        for (int mi = 0; mi < 4; ++mi) {
            __syncthreads();
            #pragma unroll
            for (int ni = 0; ni < 8; ++ni)
                #pragma unroll
                for (int rr = 0; rr < 4; ++rr) {
                    float v = acc[mi][ni][rr] + bv[ni];
                    if (relu) v = fmaxf(v, 0.f);
                    R[(lrb + rr) * 264 + cb0 + ni * 16] = f2b(v);
                }
            __syncthreads();
            #pragma unroll
            for (int p = 0; p < 4; ++p) {
                int idx = p * 256 + tid;
                int lr = idx >> 5, ch = idx & 31;
                int grow = bm + (lr >> 4) * 64 + mi * 16 + (lr & 15);
                if (grow < M)
                    *(short8*)&Cb[(size_t)z * sC + (size_t)grow * 256 + ch * 8] =
                        *(const short8*)&R[lr * 264 + ch * 8];
            }
        }
    } else {
        #pragma unroll
        for (int ni = 0; ni < 8; ++ni) {
            int col = wc + ni * 16 + fr;
            if (col >= N) continue;
            #pragma unroll
            for (int mi = 0; mi < 4; ++mi) {
                int rbase = bm + wr + mi * 16 + fq * 4;
                #pragma unroll
                for (int rr = 0; rr < 4; ++rr) {
                    int row = rbase + rr;
                    if (row >= M) continue;
                    float v = acc[mi][ni][rr] + bv[ni];
                    if (relu) v = fmaxf(v, 0.f);
                    size_t o = (size_t)z * sC + (size_t)row * N + col;
                    if (Cf) Cf[o] = v;
                    if (Cb) Cb[o] = f2b(v);
                }
            }
        }
    }
}

// ---------------------------------------------------------------------------
// Fused fc1: A row b = concat(t[src[b]], t[dst[b]], t[src]*t[dst]) built in
// the staging stage. M=8192, K=768, N=384.
// ---------------------------------------------------------------------------
__global__ __launch_bounds__(256) void fc1_fused(
    const u16* __restrict__ tb, const int* __restrict__ src, const int* __restrict__ dst,
    const u16* __restrict__ Wt, const float* __restrict__ bias, u16* __restrict__ p1b)
{
    const int z = blockIdx.z;
    const u16* T = tb + (size_t)z * NNODES * HID;
    const u16* Bt = Wt + (size_t)z * 384 * 768;
    const float* bi = bias + (size_t)z * 384;
    u16* C = p1b + (size_t)z * NPAIR * 384;

    __shared__ u16 As[128 * 32];
    __shared__ u16 Bs[128 * 32];
    const int tid  = threadIdx.x;
    const int wave = tid >> 6;
    const int lane = tid & 63;
    const int bm = blockIdx.x * 128;
    const int bn = blockIdx.y * 128;
    const int wr = (wave >> 1) * 64;
    const int wc = (wave & 1) * 64;

    const int srow = wave * 32 + (lane >> 2);
    const int scol = (lane & 3) * 8;
    const int b0 = bm + srow, b1 = b0 + 16;
    const int s0i = src[b0], d0i = dst[b0];
    const int s1i = src[b1], d1i = dst[b1];

    const u16* Bg0 = Bt + (size_t)(bn + srow) * 768 + scol;
    const u16* Bg1 = Bg0 + (size_t)16 * 768;
    u16* As0 = &As[wave * 1024];
    u16* As1 = As0 + 512;
    u16* Bs0 = &Bs[wave * 1024];
    u16* Bs1 = Bs0 + 512;
    u16* Aw0 = As0 + lane * 8;
    u16* Aw1 = As1 + lane * 8;

    const int fr = lane & 15;
    const int kg = (lane >> 4) * 8;

    f32x4 zero = {0.f, 0.f, 0.f, 0.f};
    f32x4 acc[4][4];
    #pragma unroll
    for (int mi = 0; mi < 4; ++mi)
        #pragma unroll
        for (int ni = 0; ni < 4; ++ni) acc[mi][ni] = zero;

    for (int k0 = 0; k0 < 768; k0 += 32) {
        if (k0 < 512) {
            const u16* r0p = (k0 < 256) ? (T + (size_t)s0i * HID + k0 + scol)
                                        : (T + (size_t)d0i * HID + (k0 - 256) + scol);
            const u16* r1p = (k0 < 256) ? (T + (size_t)s1i * HID + k0 + scol)
                                        : (T + (size_t)d1i * HID + (k0 - 256) + scol);
            async_copy16(r0p, As0);
            async_copy16(r1p, As1);
        } else {
            int kk = k0 - 512 + scol;
            short8 a0 = *(const short8*)&T[(size_t)s0i * HID + kk];
            short8 c0 = *(const short8*)&T[(size_t)d0i * HID + kk];
            short8 a1 = *(const short8*)&T[(size_t)s1i * HID + kk];
            short8 c1 = *(const short8*)&T[(size_t)d1i * HID + kk];
            short8 p0, p1;
            #pragma unroll
            for (int j = 0; j < 8; ++j) {
                p0[j] = (short)f2b(b2f((u16)a0[j]) * b2f((u16)c0[j]));
                p1[j] = (short)f2b(b2f((u16)a1[j]) * b2f((u16)c1[j]));
            }
            *(short8*)Aw0 = p0;
            *(short8*)Aw1 = p1;
        }
        async_copy16(Bg0 + k0, Bs0);
        async_copy16(Bg1 + k0, Bs1);
        __syncthreads();
        short8 af[4], bfr[4];
        #pragma unroll
        for (int mi = 0; mi < 4; ++mi)
            af[mi] = *(const short8*)&As[(wr + mi * 16 + fr) * 32 + kg];
        #pragma unroll
        for (int ni = 0; ni < 4; ++ni)
            bfr[ni] = *(const short8*)&Bs[(wc + ni * 16 + fr) * 32 + kg];
        #pragma unroll
        for (int mi = 0; mi < 4; ++mi)
            #pragma unroll
            for (int ni = 0; ni < 4; ++ni)
                acc[mi][ni] = __builtin_amdgcn_mfma_f32_16x16x32_bf16(
                    af[mi], bfr[ni], acc[mi][ni], 0, 0, 0);
        __syncthreads();
    }

    const int fq = lane >> 4;
    #pragma unroll
    for (int ni = 0; ni < 4; ++ni) {
        int col = bn + wc + ni * 16 + fr;
        if (col >= 384) continue;
        float bz = bi[col];
        #pragma unroll
        for (int mi = 0; mi < 4; ++mi) {
            int rbase = bm + wr + mi * 16 + fq * 4;
            #pragma unroll
            for (int r = 0; r < 4; ++r) {
                int row = rbase + r;
                float v = fmaxf(acc[mi][ni][r] + bz, 0.f);
                C[(size_t)row * 384 + col] = f2b(v);
            }
        }
    }
}

// ---------------------------------------------------------------------------
// fp32 GEMM (fc3), batched over z
// ---------------------------------------------------------------------------
#define TBM 64
#define TBN 64
#define TBK 16
__global__ void gemm_bias_b(const float* __restrict__ A, size_t sA,
                            const float* __restrict__ B, size_t sB,
                            const float* __restrict__ bias, int sBias,
                            float* __restrict__ C, size_t sC,
                            int M, int N, int K, int ldc, int relu)
{
    const int z = blockIdx.z;
    A += (size_t)z * sA; B += (size_t)z * sB;
    bias += (size_t)z * sBias; C += (size_t)z * sC;

    __shared__ float As[TBK][TBM + 1];
    __shared__ float Bs[TBK][TBN + 1];
    const int bm = blockIdx.x * TBM;
    const int bn = blockIdx.y * TBN;
    const int tid = threadIdx.x;
    const int tm = (tid / 16) * 4;
    const int tn = (tid % 16) * 4;
    float acc[4][4] = {};

    for (int k0 = 0; k0 < K; k0 += TBK) {
        #pragma unroll
        for (int l = 0; l < 4; ++l) {
            int idx = tid + l * 256;
            int m = idx / TBK, k = idx % TBK;
            int gm = bm + m;
            float v = 0.f;
            if (gm < M) v = A[(size_t)gm * K + k0 + k];
            As[k][m] = v;
        }
        #pragma unroll
        for (int l = 0; l < 4; ++l) {
            int idx = tid + l * 256;
            int k = idx / TBN, n = idx % TBN;
            int gn = bn + n;
            float v = 0.f;
            if (gn < N) v = B[(size_t)(k0 + k) * N + gn];
            Bs[k][n] = v;
        }
        __syncthreads();
        #pragma unroll
        for (int k = 0; k < TBK; ++k) {
            float a[4], b[4];
            #pragma unroll
            for (int i = 0; i < 4; ++i) a[i] = As[k][tm + i];
            #pragma unroll
            for (int j = 0; j < 4; ++j) b[j] = Bs[k][tn + j];
            #pragma unroll
            for (int i = 0; i < 4; ++i)
                #pragma unroll
                for (int j = 0; j < 4; ++j)
                    acc[i][j] = fmaf(a[i], b[j], acc[i][j]);
        }
        __syncthreads();
    }
    #pragma unroll
    for (int i = 0; i < 4; ++i) {
        int gm = bm + tm + i;
        if (gm >= M) continue;
        #pragma unroll
        for (int j = 0; j < 4; ++j) {
            int gn = bn + tn + j;
            if (gn >= N) continue;
            float v = acc[i][j] + bias[gn];
            if (relu) v = fmaxf(v, 0.f);
            C[(size_t)gm * ldc + gn] = v;
        }
    }
}

// ---------------------------------------------------------------------------
// Setup kernels
// ---------------------------------------------------------------------------
__global__ void xconv(const float* __restrict__ x, u16* __restrict__ xb)
{
    int gid = blockIdx.x * blockDim.x + threadIdx.x;
    int i4 = gid * 4;
    int row = i4 >> 9;
    float4 v = make_float4(0.f, 0.f, 0.f, 0.f);
    if (row < NNODES) v = *(const float4*)&x[i4];
    *(ushort4*)&xb[i4] = f2b4(v.x, v.y, v.z, v.w);
}

// W f32 [nm][K][N] -> Wt bf16 [nm][NP][K]
__global__ void wtrans(const float* __restrict__ W, u16* __restrict__ Wt,
                       int K, int N, int NP)
{
    __shared__ float tile[32][33];
    const int m = blockIdx.z;
    const int k0 = blockIdx.x * 32, n0 = blockIdx.y * 32;
    const float* Wm = W + (size_t)m * K * N;
    u16* Wtm = Wt + (size_t)m * NP * K;
    const int c = threadIdx.x & 31, r = threadIdx.x >> 5;
    #pragma unroll
    for (int p = 0; p < 4; ++p)
        tile[r + p * 8][c] = Wm[(size_t)(k0 + r + p * 8) * N + n0 + c];
    __syncthreads();
    #pragma unroll
    for (int p = 0; p < 4; ++p)
        Wtm[(size_t)(n0 + r + p * 8) * K + k0 + c] = f2b(tile[c][r + p * 8]);
}

// CSR build: ptrs layout [14][20001]; 0..6 = by-col (class i), 7..13 = by-row.
__device__ __forceinline__ int swz3584(int b) { return (b & 7) * 448 + (b >> 3); }

__global__ void hist(const int* __restrict__ edges, int* __restrict__ ptrs)
{
    int gid = swz3584(blockIdx.x) * 256 + threadIdx.x;
    int i = gid >> 17, e = gid & (NEDGE - 1);
    const int* eb = edges + (size_t)i * 2 * NEDGE;
    int r = eb[e], c = eb[NEDGE + e];
    atomicAdd(&ptrs[i * 20001 + c + 1], 1);
    atomicAdd(&ptrs[(7 + i) * 20001 + r + 1], 1);
}

#define SCN 512
__global__ void scan1(int* __restrict__ ptrs, int* __restrict__ aux)
{
    __shared__ int s[SCN];
    const int a = blockIdx.y;
    const int t = threadIdx.x;
    const int idx = blockIdx.x * SCN + t;
    int* arr = ptrs + a * 20001;
    int v = (idx < 20001) ? arr[idx] : 0;
    s[t] = v;
    __syncthreads();
    for (int off = 1; off < SCN; off <<= 1) {
        int x = (t >= off) ? s[t - off] : 0;
        __syncthreads();
        s[t] += x;
        __syncthreads();
    }
    if (idx < 20001) arr[idx] = s[t];
    if (t == SCN - 1) aux[a * 40 + blockIdx.x] = s[t];
}
__global__ void scan2(int* __restrict__ aux)
{
    if (threadIdx.x != 0) return;
    int a = blockIdx.x;
    int run = 0;
    for (int b = 0; b < 40; ++b) {
        int t = aux[a * 40 + b];
        aux[a * 40 + b] = run;
        run += t;
    }
}
__global__ void scan3(int* __restrict__ ptrs, const int* __restrict__ aux,
                      int* __restrict__ cur)
{
    const int a = blockIdx.y;
    const int idx = blockIdx.x * SCN + threadIdx.x;
    if (idx < 20001) {
        int v = ptrs[a * 20001 + idx] + aux[a * 40 + blockIdx.x];
        ptrs[a * 20001 + idx] = v;
        cur[a * 20001 + idx] = v;
    }
}
__global__ void csrfill(const int* __restrict__ edges, int* __restrict__ cur,
                        int* __restrict__ othercol, int* __restrict__ otherrow)
{
    int gid = swz3584(blockIdx.x) * 256 + threadIdx.x;
    int i = gid >> 17, e = gid & (NEDGE - 1);
    const int* eb = edges + (size_t)i * 2 * NEDGE;
    int r = eb[e], c = eb[NEDGE + e];
    int pc = atomicAdd(&cur[i * 20001 + c], 1);
    othercol[(size_t)i * NEDGE + pc] = r;
    int pr = atomicAdd(&cur[(7 + i) * 20001 + r], 1);
    otherrow[(size_t)i * NEDGE + pr] = c;
}
__global__ void mkdinv(const int* __restrict__ ptrs, float* __restrict__ dinv)
{
    int gid = blockIdx.x * blockDim.x + threadIdx.x;
    if (gid >= NCLS * NNODES) return;
    int i = gid / NNODES, n = gid - i * NNODES;
    int d = ptrs[i * 20001 + n + 1] - ptrs[i * 20001 + n];
    dinv[gid] = rsqrtf((float)d + 1.0f);
}

// ---------------------------------------------------------------------------
// BatchNorm (batched over z = blockIdx.y)
// ---------------------------------------------------------------------------
#define STAT_ROWS 128
__global__ void colstats_b(const u16* __restrict__ xwb, float* __restrict__ stats)
{
    const int z = blockIdx.y;
    const int f = threadIdx.x;
    const int r0 = blockIdx.x * STAT_ROWS;
    const int r1 = min(r0 + STAT_ROWS, NNODES);
    const u16* X = xwb + (size_t)z * NNODES * HID;
    float s = 0.f, sq = 0.f;
    for (int r = r0; r < r1; ++r) {
        float v = b2f(X[(size_t)r * HID + f]);
        s += v; sq += v * v;
    }
    atomAddF(&stats[z * 2 * HID + f], s);
    atomAddF(&stats[z * 2 * HID + HID + f], sq);
}
__global__ void bn_relu_b(const u16* __restrict__ xwb, const float* __restrict__ stats,
                          const float* __restrict__ gamma, const float* __restrict__ beta,
                          u16* __restrict__ tb)
{
    const int z = blockIdx.y;
    const int gid = blockIdx.x * blockDim.x + threadIdx.x;   // NNODES*64
    const int n = gid >> 6, f4 = (gid & 63) * 4;
    const u16* X = xwb + (size_t)z * NNODES * HID;
    u16* T = tb + (size_t)z * NNODES * HID;
    const float* st = stats + z * 2 * HID;
    const float invN = 1.0f / NNODES;
    float4 su = *(const float4*)&st[f4];
    float4 sq = *(const float4*)&st[HID + f4];
    float4 g  = *(const float4*)&gamma[(size_t)z * HID + f4];
    float4 be = *(const float4*)&beta[(size_t)z * HID + f4];
    ushort4 u = *(const ushort4*)&X[(size_t)n * HID + f4];
    float4 x = b2f4(u);
    float o[4], mu, var;
    mu = su.x * invN; var = sq.x * invN - mu * mu;
    o[0] = fmaxf((x.x - mu) * rsqrtf(var + BN_EPS) * g.x + be.x, 0.f);
    mu = su.y * invN; var = sq.y * invN - mu * mu;
    o[1] = fmaxf((x.y - mu) * rsqrtf(var + BN_EPS) * g.y + be.y, 0.f);
    mu = su.z * invN; var = sq.z * invN - mu * mu;
    o[2] = fmaxf((x.z - mu) * rsqrtf(var + BN_EPS) * g.z + be.z, 0.f);
    mu = su.w * invN; var = sq.w * invN - mu * mu;
    o[3] = fmaxf((x.w - mu) * rsqrtf(var + BN_EPS) * g.w + be.w, 0.f);
    *(ushort4*)&T[(size_t)n * HID + f4] = f2b4(o[0], o[1], o[2], o[3]);
}

// ---------------------------------------------------------------------------
// Graph aggregation: 1D grid, class->XCD chunk swizzle; wave/node, lane=4 feats
// ---------------------------------------------------------------------------
__global__ void agg_prod_s(const u16* __restrict__ tb, const int* __restrict__ rptrs,
                           const int* __restrict__ roth, u16* __restrict__ prodb,
                           int nwg)
{
    const int logical = chunk_swz(blockIdx.x, nwg);
    const int z = logical / 5000, nb = logical % 5000;
    const u16* T = tb + (size_t)z * NNODES * HID;
    const int* rptr = rptrs + (size_t)z * 20001;
    const int* oth = roth + (size_t)z * NEDGE;
    u16* P = prodb + (size_t)z * NNODES * HID;
    const int node = nb * 4 + (threadIdx.x >> 6);
    const int f = (threadIdx.x & 63) * 4;
    const int s0 = rptr[node], s1 = rptr[node + 1];
    float ax = 0.f, ay = 0.f, az = 0.f, aw = 0.f;
    for (int e = s0; e < s1; ++e) {
        int c = oth[e];
        ushort4 u = *(const ushort4*)&T[(size_t)c * HID + f];
        ax += b2f(u.x); ay += b2f(u.y); az += b2f(u.z); aw += b2f(u.w);
    }
    ushort4 tv = *(const ushort4*)&T[(size_t)node * HID + f];
    *(ushort4*)&P[(size_t)node * HID + f] =
        f2b4(b2f(tv.x) * ax, b2f(tv.y) * ay, b2f(tv.z) * az, b2f(tv.w) * aw);
}

// out = relu(dn*(dn*xw[n] + sum dr*xw[r]) + gb) + msg(in out buf) + degrow*db
__global__ void conv_gather_s(const u16* __restrict__ xwb, const int* __restrict__ cptrs,
                              const int* __restrict__ coth, const float* __restrict__ dinv,
                              const int* __restrict__ rptrs,
                              const float* __restrict__ gb, const float* __restrict__ db,
                              u16* __restrict__ tbout, int nwg)
{
    const int logical = chunk_swz(blockIdx.x, nwg);
    const int z = logical / 5000, nb = logical % 5000;
    const u16* X = xwb + (size_t)z * NNODES * HID;
    const int* cptr = cptrs + (size_t)z * 20001;
    const int* oth = coth + (size_t)z * NEDGE;
    const float* dv = dinv + (size_t)z * NNODES;
    const int* rptr = rptrs + (size_t)z * 20001;
    const float* g4p = gb + (size_t)z * NLAY * HID;
    const float* d4p = db + (size_t)z * NLAY * HID;
    u16* O = tbout + (size_t)z * NNODES * HID;

    const int node = nb * 4 + (threadIdx.x >> 6);
    const int f = (threadIdx.x & 63) * 4;
    const float dn = dv[node];
    const int s0 = cptr[node], s1 = cptr[node + 1];
    ushort4 su = *(const ushort4*)&X[(size_t)node * HID + f];
    float ax = dn * b2f(su.x), ay = dn * b2f(su.y);
    float az = dn * b2f(su.z), aw = dn * b2f(su.w);
    for (int e = s0; e < s1; ++e) {
        int r = oth[e];
        float dr = dv[r];
        ushort4 u = *(const ushort4*)&X[(size_t)r * HID + f];
        ax += dr * b2f(u.x); ay += dr * b2f(u.y);
        az += dr * b2f(u.z); aw += dr * b2f(u.w);
    }
    float4 g  = *(const float4*)&g4p[f];
    float4 d4 = *(const float4*)&d4p[f];
    float degr = (float)(rptr[node + 1] - rptr[node]);
    ushort4 mu = *(const ushort4*)&O[(size_t)node * HID + f];
    float ox = fmaxf(ax * dn + g.x, 0.f) + b2f(mu.x) + degr * d4.x;
    float oy = fmaxf(ay * dn + g.y, 0.f) + b2f(mu.y) + degr * d4.y;
    float oz = fmaxf(az * dn + g.z, 0.f) + b2f(mu.z) + degr * d4.z;
    float ow = fmaxf(aw * dn + g.w, 0.f) + b2f(mu.w) + degr * d4.w;
    *(ushort4*)&O[(size_t)node * HID + f] = f2b4(ox, oy, oz, ow);
}

__global__ void final_cls(const float* __restrict__ outs, const float* __restrict__ clsW,
                          const float* __restrict__ clsb, float* __restrict__ out)
{
    const int gid = blockIdx.x * blockDim.x + threadIdx.x;
    if (gid >= NPAIR * NCLS) return;
    const int b = gid / NCLS, c = gid % NCLS;
    float acc = clsb[c];
    const float* row = outs + (size_t)b * 112;
    #pragma unroll 4
    for (int k = 0; k < 112; ++k)
        acc = fmaf(fmaxf(row[k], 0.f), clsW[k * NCLS + c], acc);
    out[gid] = acc;
}

// ---------------------------------------------------------------------------
extern "C" void kernel_launch(void* const* d_in, const int* in_sizes, int n_in,
                              void* d_out, int out_size, void* d_ws, size_t ws_size,
                              hipStream_t stream)
{
    const float* x        = (const float*)d_in[0];
    const int*   edges    = (const int*)  d_in[1];
    const int*   node_id  = (const int*)  d_in[2];
    const float* lin0_W   = (const float*)d_in[3];
    const float* lin0_b   = (const float*)d_in[4];
    const float* bn_gamma = (const float*)d_in[5];
    const float* bn_beta  = (const float*)d_in[6];
    const float* gcn_W    = (const float*)d_in[7];
    const float* gcn_b    = (const float*)d_in[8];
    const float* dp_W     = (const float*)d_in[9];
    const float* dp_b     = (const float*)d_in[10];
    const float* fc1_W    = (const float*)d_in[11];
    const float* fc1_b    = (const float*)d_in[12];
    const float* fc2_W    = (const float*)d_in[13];
    const float* fc2_b    = (const float*)d_in[14];
    const float* fc3_W    = (const float*)d_in[15];
    const float* fc3_b    = (const float*)d_in[16];
    const float* cls_W    = (const float*)d_in[17];
    const float* cls_b    = (const float*)d_in[18];
    float* out = (float*)d_out;

    unsigned char* w = (unsigned char*)d_ws;
    size_t used = 0;
    auto alloc = [&](size_t bytes) {
        void* p = (void*)(w + used);
        used += (bytes + 255) & ~(size_t)255;
        return p;
    };
    u16*   xb       = (u16*)  alloc((size_t)MPAD * DIN * 2);
    u16*   lin0Wt   = (u16*)  alloc((size_t)NCLS * HID * DIN * 2);
    u16*   gcnWt    = (u16*)  alloc((size_t)NCLS * NLAY * HID * HID * 2);
    u16*   dpWt     = (u16*)  alloc((size_t)NCLS * NLAY * HID * HID * 2);
    u16*   fc1Wt    = (u16*)  alloc((size_t)NCLS * 384 * 768 * 2);
    u16*   fc2Wt    = (u16*)  alloc((size_t)NCLS * 256 * 384 * 2);
    int*   ptrs     = (int*)  alloc((size_t)14 * 20001 * 4);
    int*   cur      = (int*)  alloc((size_t)14 * 20001 * 4);
    int*   aux      = (int*)  alloc((size_t)14 * 40 * 4);
    int*   othercol = (int*)  alloc((size_t)NCLS * NEDGE * 4);
    int*   otherrow = (int*)  alloc((size_t)NCLS * NEDGE * 4);
    float* dinv     = (float*)alloc((size_t)NCLS * NNODES * 4);
    float* outsb    = (float*)alloc((size_t)NPAIR * 112 * 4);
    float* stats    = (float*)alloc((size_t)NCLS * 2 * HID * 4);

    int g = 1;
    for (int t = NCLS; t >= 1; --t) {
        size_t big = ((size_t)t * NNODES + 96) * HID * 2;
        big = (big + 255) & ~(size_t)255;
        if (used + 3 * big <= ws_size) { g = t; break; }
    }
    size_t bigBytes = ((size_t)g * NNODES + 96) * HID * 2;
    u16* tbA = (u16*)alloc(bigBytes);
    u16* tbB = (u16*)alloc(bigBytes);
    u16* pxw = (u16*)alloc(bigBytes);
    u16*   p1b = pxw;            // head stage reuse
    float* p2f = (float*)tbB;    // head stage reuse

    const int* src = node_id;
    const int* dst = node_id + NPAIR;

    // ---- setup ----
    xconv<<<(MPAD * DIN / 4) / 256, 256, 0, stream>>>(x, xb);
    wtrans<<<dim3(16, 8, 7),  256, 0, stream>>>(lin0_W, lin0Wt, 512, 256, 256);
    wtrans<<<dim3(8, 8, 14),  256, 0, stream>>>(gcn_W,  gcnWt,  256, 256, 256);
    wtrans<<<dim3(8, 8, 14),  256, 0, stream>>>(dp_W,   dpWt,   256, 256, 256);
    wtrans<<<dim3(24, 12, 7), 256, 0, stream>>>(fc1_W,  fc1Wt,  768, 384, 384);
    wtrans<<<dim3(12, 6, 7),  256, 0, stream>>>(fc2_W,  fc2Wt,  384, 192, 256);

    hipMemsetAsync(ptrs, 0, (size_t)14 * 20001 * 4, stream);
    hist<<<(NCLS * NEDGE) / 256, 256, 0, stream>>>(edges, ptrs);
    scan1<<<dim3(40, 14), SCN, 0, stream>>>(ptrs, aux);
    scan2<<<14, 64, 0, stream>>>(aux);
    scan3<<<dim3(40, 14), SCN, 0, stream>>>(ptrs, aux, cur);
    csrfill<<<(NCLS * NEDGE) / 256, 256, 0, stream>>>(edges, cur, othercol, otherrow);
    mkdinv<<<(NCLS * NNODES + 255) / 256, 256, 0, stream>>>(ptrs, dinv);

    const size_t sT = (size_t)NNODES * HID;

    for (int cb = 0; cb < NCLS; cb += g) {
        const int gl = min(g, NCLS - cb);
        const int nwg = gl * 5000;
        u16* tb_cur = tbA;
        u16* tb_nxt = tbB;

        // lin0 (A shared) -> pxw ; BN+ReLU -> tbA
        gemm_fn<<<dim3(157, 1, gl), 256, 0, stream>>>(
            xb, 0, lin0Wt + (size_t)cb * HID * DIN, (size_t)HID * DIN,
            lin0_b + cb * HID, HID, nullptr, pxw, sT, NNODES, HID, DIN, 0);
        hipMemsetAsync(stats, 0, (size_t)gl * 2 * HID * 4, stream);
        colstats_b<<<dim3(157, gl), HID, 0, stream>>>(pxw, stats);
        bn_relu_b<<<dim3(5000, gl), 256, 0, stream>>>(
            pxw, stats, bn_gamma + cb * HID, bn_beta + cb * HID, tb_cur);

        for (int j = 0; j < NLAY; ++j) {
            const u16* gWt = gcnWt + ((size_t)cb * NLAY + j) * HID * HID;
            const u16* dWt = dpWt  + ((size_t)cb * NLAY + j) * HID * HID;
            const float* gb = gcn_b + ((size_t)cb * NLAY + j) * HID;
            const float* db = dp_b  + ((size_t)cb * NLAY + j) * HID;

            agg_prod_s<<<nwg, 256, 0, stream>>>(
                tb_cur, ptrs + (7 + cb) * 20001, otherrow + (size_t)cb * NEDGE, pxw, nwg);
            gemm_fn<<<dim3(157, 1, gl), 256, 0, stream>>>(
                pxw, sT, dWt, (size_t)NLAY * HID * HID, nullptr, 0,
                nullptr, tb_nxt, sT, NNODES, HID, HID, 0);
            gemm_fn<<<dim3(157, 1, gl), 256, 0, stream>>>(
                tb_cur, sT, gWt, (size_t)NLAY * HID * HID, nullptr, 0,
                nullptr, pxw, sT, NNODES, HID, HID, 0);
            conv_gather_s<<<nwg, 256, 0, stream>>>(
                pxw, ptrs + cb * 20001, othercol + (size_t)cb * NEDGE,
                dinv + (size_t)cb * NNODES, ptrs + (7 + cb) * 20001,
                gb, db, tb_nxt, nwg);

            u16* tmp = tb_cur; tb_cur = tb_nxt; tb_nxt = tmp;
        }

        // head
        fc1_fused<<<dim3(64, 3, gl), 256, 0, stream>>>(
            tb_cur, src, dst, fc1Wt + (size_t)cb * 384 * 768, fc1_b + cb * 384, p1b);
        gemm_fn<<<dim3(64, 1, gl), 256, 0, stream>>>(
            p1b, (size_t)NPAIR * 384, fc2Wt + (size_t)cb * 256 * 384, (size_t)256 * 384,
            fc2_b + cb * 192, 192, p2f, nullptr, (size_t)NPAIR * 192,
            NPAIR, 192, 384, 1);
        gemm_bias_b<<<dim3(128, 1, gl), 256, 0, stream>>>(
            p2f, (size_t)NPAIR * 192, fc3_W + (size_t)cb * 192 * 16, (size_t)192 * 16,
            fc3_b + cb * 16, 16, outsb + cb * 16, 16,
            NPAIR, 16, 192, 112, 0);
    }

    final_cls<<<(NPAIR * NCLS + 255) / 256, 256, 0, stream>>>(outsb, cls_W, cls_b, out);
}